// Round 7
// baseline (776.518 us; speedup 1.0000x reference)
//
#include <hip/hip_runtime.h>
#include <hip/hip_bf16.h>
#include <math.h>

typedef unsigned short u16;
typedef unsigned int u32;
typedef __attribute__((ext_vector_type(8))) short short8;
typedef __attribute__((ext_vector_type(8))) u16 ushort8;
typedef __attribute__((ext_vector_type(4))) float f32x4;

#define N_B 4
#define L_S 2048
#define E_D 2048
#define NH 16
#define HD 128
#define WIN 1024
#define QW 3072  // QKV buffer row width: 2048 q | 512 k | 512 v
#define LOG2E 1.4426950408889634f

static __device__ __forceinline__ u16 f32_bf16(float f) {
  u32 u = __builtin_bit_cast(u32, f);
  u = (u + 0x7fffu + ((u >> 16) & 1u)) >> 16;  // RNE
  return (u16)u;
}
static __device__ __forceinline__ float bf16_f32(u16 h) {
  u32 u = ((u32)h) << 16;
  return __builtin_bit_cast(float, u);
}
static __device__ __forceinline__ void gload_lds16(const void* g, void* l) {
  __builtin_amdgcn_global_load_lds((__attribute__((address_space(1))) void*)g,
                                   (__attribute__((address_space(3))) void*)l, 16, 0, 0);
}

// ---------------- fp32 -> bf16 cast (n multiple of 8) ----------------
__global__ void k_cast(const float* __restrict__ src, u16* __restrict__ dst, int n8) {
  int i = blockIdx.x * blockDim.x + threadIdx.x;
  if (i >= n8) return;
  const float4* s = (const float4*)src + (size_t)i * 2;
  float4 a = s[0], b = s[1];
  ushort8 v;
  v[0] = f32_bf16(a.x); v[1] = f32_bf16(a.y); v[2] = f32_bf16(a.z); v[3] = f32_bf16(a.w);
  v[4] = f32_bf16(b.x); v[5] = f32_bf16(b.y); v[6] = f32_bf16(b.z); v[7] = f32_bf16(b.w);
  *((ushort8*)dst + i) = v;
}

// ---------------- RoPE cos/sin table: [L][64] ----------------
__global__ void k_rope_table(float* __restrict__ cs, float* __restrict__ sn) {
  int idx = blockIdx.x * blockDim.x + threadIdx.x;  // 2048*64
  int l = idx >> 6, f = idx & 63;
  float freq = exp2f(-(float)f * (13.287712379549449f / 64.0f));  // 10000^(-2f/128)
  float ang = (float)l * freq;
  cs[idx] = cosf(ang);
  sn[idx] = sinf(ang);
}

// ---------------- interleaved RoPE applied in place to Q and K of QKV ----------------
__global__ void k_rope_apply(u16* __restrict__ QKV, const float* __restrict__ cs,
                             const float* __restrict__ sn) {
  int idx = blockIdx.x * blockDim.x + threadIdx.x;  // 8192*20*64 exactly
  int f = idx & 63;
  int rest = idx >> 6;
  int hh = rest % 20;          // 0..15 q heads, 16..19 kv heads
  int row = rest / 20;         // 0..8191 (= n*L + l)
  int l = row & (L_S - 1);
  int col = (hh < NH) ? (hh * HD + 2 * f) : (E_D + (hh - NH) * HD + 2 * f);
  u32* p = (u32*)(QKV + (size_t)row * QW + col);
  u32 v = *p;
  float xr = bf16_f32((u16)(v & 0xffffu));
  float xi = bf16_f32((u16)(v >> 16));
  float c = cs[l * 64 + f], s = sn[l * 64 + f];
  float orr = xr * c - xi * s;
  float oii = xr * s + xi * c;
  *p = (u32)f32_bf16(orr) | ((u32)f32_bf16(oii) << 16);
}

// ---------------- C = A @ B^T, bf16 in, bf16 or f32 out ----------------
// A: MxK row-major (lda), B: NxK row-major (ldb). 128x128 tile, BK=64, 4 waves.
// XCD-aware block swizzle (T1): nwg%8==0 for both launches -> bijective.
template <int OUT_F32>
__global__ __launch_bounds__(256) void k_gemm_bt(
    const u16* __restrict__ A, int lda,
    const u16* __restrict__ B, int ldb,
    void* __restrict__ Cp, int ldc, int K) {
  __shared__ __align__(16) u16 As[128 * 64];
  __shared__ __align__(16) u16 Bs[128 * 64];
  const int tid = threadIdx.x;
  const int lane = tid & 63, w = tid >> 6;
  const int lr = lane & 15, lg = lane >> 4;
  const int gx = gridDim.x, nwg = gx * gridDim.y;
  const int fid = blockIdx.y * gx + blockIdx.x;
  const int cpx = nwg >> 3;
  const int sid = (fid & 7) * cpx + (fid >> 3);
  const int m0 = (sid % gx) * 128, n0 = (sid / gx) * 128;
  const int wm = (w >> 1) * 64, wn = (w & 1) * 64;
  const int srow = tid >> 3, scol = (tid & 7) * 8;  // staging: 16B per lane
  const f32x4 z4 = {0.f, 0.f, 0.f, 0.f};
  f32x4 acc[4][4];
#pragma unroll
  for (int i = 0; i < 4; ++i)
#pragma unroll
    for (int j = 0; j < 4; ++j) acc[i][j] = z4;
  for (int kt = 0; kt < K; kt += 64) {
#pragma unroll
    for (int rr = 0; rr < 4; ++rr) {
      gload_lds16(A + (size_t)(m0 + rr * 32 + srow) * lda + kt + scol,
                  (char*)As + rr * 4096 + w * 1024);
      gload_lds16(B + (size_t)(n0 + rr * 32 + srow) * ldb + kt + scol,
                  (char*)Bs + rr * 4096 + w * 1024);
    }
    __syncthreads();
#pragma unroll
    for (int kk = 0; kk < 64; kk += 32) {
      short8 af[4], bfr[4];
#pragma unroll
      for (int mi = 0; mi < 4; ++mi)
        af[mi] = *(const short8*)(As + (wm + mi * 16 + lr) * 64 + kk + lg * 8);
#pragma unroll
      for (int ni = 0; ni < 4; ++ni)
        bfr[ni] = *(const short8*)(Bs + (wn + ni * 16 + lr) * 64 + kk + lg * 8);
#pragma unroll
      for (int mi = 0; mi < 4; ++mi)
#pragma unroll
        for (int ni = 0; ni < 4; ++ni)
          acc[mi][ni] =
              __builtin_amdgcn_mfma_f32_16x16x32_bf16(af[mi], bfr[ni], acc[mi][ni], 0, 0, 0);
    }
    __syncthreads();
  }
#pragma unroll
  for (int mi = 0; mi < 4; ++mi)
#pragma unroll
    for (int ni = 0; ni < 4; ++ni)
#pragma unroll
      for (int j = 0; j < 4; ++j) {
        size_t r = (size_t)(m0 + wm + mi * 16 + lg * 4 + j);
        int c = n0 + wn + ni * 16 + lr;
        if (OUT_F32)
          ((float*)Cp)[r * ldc + c] = acc[mi][ni][j];
        else
          ((u16*)Cp)[r * ldc + c] = f32_bf16(acc[mi][ni][j]);
      }
}

// ---------------- sliding-window flash attention (pipelined, 8 waves) ----------------
// Grid (L/128, H, N). 8 waves; wave w owns q-rows [qb*128+w*16, +16). KV tile = 64.
// Double-buffered K (global_load_lds, pre-swizzled source) and V (reg-staged,
// swizzled ds_write). One barrier per tile: barrier1 drains prefetched K(t+1)/V(t+1)
// and orders all cross-wave LDS reuse (audited: K[c^1] writes vs QK^T(t-1) reads
// separated by barrier1(t-1); Vt[c] rewrites at t+1 ordered after all PV(t) reads
// because barrier1(t+1) gates them; Plds is wave-private).
__global__ __launch_bounds__(512, 4) void k_attn(u16* __restrict__ QKV) {
  const int qb = blockIdx.x, h = blockIdx.y, b = blockIdx.z;
  const int tid = threadIdx.x;
  const int lane = tid & 63, w = tid >> 6;      // 8 waves
  const int lr = lane & 15, lg = lane >> 4;
  const int kh = h >> 2;
  const int qs = qb * 128 + w * 16;
  __shared__ __align__(16) u16 Klds[2][64 * 128];  // [kv][d], swizzled, 2 buffers
  __shared__ __align__(16) u16 Vt[2][128 * 64];    // [d][kv], swizzled, 2 buffers
  __shared__ __align__(16) u16 Plds[8][16 * 64];   // per-wave P, swizzled
  char* Pb = (char*)(&Plds[w][0]);
  const int swz = (lr & 7) << 4;                   // read swizzle (row = *16 + lr)
  const float scale = 0.08838834764831845f;        // 1/sqrt(128)
  const size_t bL = (size_t)b * L_S;
  const size_t rowQ = (bL + qs + lr) * QW + h * HD;
  short8 qf[4];
#pragma unroll
  for (int c = 0; c < 4; ++c) qf[c] = *(const short8*)(QKV + rowQ + c * 32 + lg * 8);
  const f32x4 z4 = {0.f, 0.f, 0.f, 0.f};
  f32x4 o[8];
#pragma unroll
  for (int dt = 0; dt < 8; ++dt) o[dt] = z4;
  float mrow[4], lrow[4];
#pragma unroll
  for (int j = 0; j < 4; ++j) { mrow[j] = -3e38f; lrow[j] = 0.f; }
  int t0 = qb * 128 - (WIN - 1);
  if (t0 < 0) t0 = 0;
  t0 >>= 6;
  const int t1 = 2 * qb + 1;  // == (qb*128+127)>>6
  short8 vreg[2];

  // --- staging helpers (512 threads) ---
  auto ISSUE_K = [&](int t, int buf) {
    char* Kb = (char*)Klds + buf * 16384;
#pragma unroll
    for (int rr = 0; rr < 2; ++rr) {
      int row = rr * 32 + (tid >> 4);              // 0..63
      int colb = ((tid & 15) * 16) ^ ((row & 7) << 4);  // inverse-swizzled source
      gload_lds16(QKV + (bL + t * 64 + row) * QW + E_D + kh * HD + (colb >> 1),
                  Kb + rr * 8192 + w * 1024 + (lane << 4));
    }
  };
  auto LOAD_V = [&](int t) {
#pragma unroll
    for (int rr = 0; rr < 2; ++rr)
      vreg[rr] = *(const short8*)(QKV + (bL + t * 64 + lane) * QW + E_D + 512 + kh * HD +
                                  ((w * 2 + rr) * 8));
  };
  auto WRITE_V = [&](int buf) {
    char* Vb = (char*)Vt + buf * 16384;
#pragma unroll
    for (int rr = 0; rr < 2; ++rr) {
      int db = (w * 2 + rr) * 8;                   // multiple of 8 -> row&7 == e
#pragma unroll
      for (int e = 0; e < 8; ++e)
        *(u16*)(Vb + ((((db + e) * 128) + lane * 2) ^ (e << 4))) = (u16)vreg[rr][e];
    }
  };

  // --- prologue: stage tile t0 ---
  LOAD_V(t0);
  ISSUE_K(t0, 0);
  __syncthreads();          // drains K gloads + V reg loads
  WRITE_V(0);               // Vt[0] visible to all waves after barrier1 of iter t0
  int c = 0;

  for (int t = t0; t <= t1; ++t) {
    const int kv0 = t * 64;
    const int tn = (t < t1) ? t + 1 : t1;
    // prefetch next tile: K -> Klds[c^1] (async), V -> regs. Both fly until barrier1.
    ISSUE_K(tn, c ^ 1);
    LOAD_V(tn);
    // --- S = Q K^T from Klds[c]: 4 col-tiles of 16 ---
    char* Kb = (char*)Klds + c * 16384;
    f32x4 s[4];
#pragma unroll
    for (int tile = 0; tile < 4; ++tile) s[tile] = z4;
#pragma unroll
    for (int tile = 0; tile < 4; ++tile)
#pragma unroll
      for (int cc = 0; cc < 4; ++cc) {
        short8 kf = *(const short8*)(Kb + (((tile * 16 + lr) * 256 + cc * 64 + lg * 16) ^ swz));
        s[tile] = __builtin_amdgcn_mfma_f32_16x16x32_bf16(qf[cc], kf, s[tile], 0, 0, 0);
      }
    // --- online softmax (rows = lg*4+j; cols = kv0 + tile*16 + lr) ---
    float p[4][4], pmax[4];
#pragma unroll
    for (int j = 0; j < 4; ++j) {
      int gr = qs + lg * 4 + j;
      float mx = -3e38f;
#pragma unroll
      for (int tile = 0; tile < 4; ++tile) {
        int g = kv0 + tile * 16 + lr;
        bool a = (g <= gr) && (g > gr - WIN);
        float v = a ? s[tile][j] * scale : -3e38f;
        p[tile][j] = v;
        mx = fmaxf(mx, v);
      }
      mx = fmaxf(mx, __shfl_xor(mx, 1));
      mx = fmaxf(mx, __shfl_xor(mx, 2));
      mx = fmaxf(mx, __shfl_xor(mx, 4));
      mx = fmaxf(mx, __shfl_xor(mx, 8));
      pmax[j] = mx;
    }
    // defer-max (T13): rescale only when some row's max grew by > 8
    bool needr = (pmax[0] > mrow[0] + 8.f) || (pmax[1] > mrow[1] + 8.f) ||
                 (pmax[2] > mrow[2] + 8.f) || (pmax[3] > mrow[3] + 8.f);
    if (__ballot(needr)) {
      float al[4];
#pragma unroll
      for (int j = 0; j < 4; ++j) {
        float mn = fmaxf(mrow[j], pmax[j]);
        al[j] = exp2f((mrow[j] - mn) * LOG2E);
        mrow[j] = mn;
        lrow[j] *= al[j];
      }
#pragma unroll
      for (int dt = 0; dt < 8; ++dt) {
        o[dt][0] *= al[0]; o[dt][1] *= al[1]; o[dt][2] *= al[2]; o[dt][3] *= al[3];
      }
    }
#pragma unroll
    for (int j = 0; j < 4; ++j) {
      float rs = 0.f;
#pragma unroll
      for (int tile = 0; tile < 4; ++tile) {
        float pe = (p[tile][j] > -1e37f) ? exp2f((p[tile][j] - mrow[j]) * LOG2E) : 0.f;
        p[tile][j] = pe;
        rs += pe;
      }
      rs += __shfl_xor(rs, 1);
      rs += __shfl_xor(rs, 2);
      rs += __shfl_xor(rs, 4);
      rs += __shfl_xor(rs, 8);
      lrow[j] += rs;
      int R = lg * 4 + j;
      int rswz = (R & 7) << 4;
#pragma unroll
      for (int tile = 0; tile < 4; ++tile)
        *(u16*)(Pb + ((R * 128 + (tile * 16 + lr) * 2) ^ rswz)) = f32_bf16(p[tile][j]);
    }
    __syncthreads();  // barrier1: drains K(tn)+V(tn); P + Vt[c] visible; orders reuse
    // stage V(tn) into the spare buffer (PV below reads Vt[c], no overlap)
    WRITE_V(c ^ 1);
    // --- O += P V from Vt[c] ---
    char* Vb = (char*)Vt + c * 16384;
    short8 pf0 = *(const short8*)(Pb + ((lr * 128 + 0 + lg * 16) ^ swz));
    short8 pf1 = *(const short8*)(Pb + ((lr * 128 + 64 + lg * 16) ^ swz));
    __builtin_amdgcn_s_setprio(1);
#pragma unroll
    for (int dt = 0; dt < 8; ++dt) {
      short8 vf0 = *(const short8*)(Vb + (((dt * 16 + lr) * 128 + 0 + lg * 16) ^ swz));
      short8 vf1 = *(const short8*)(Vb + (((dt * 16 + lr) * 128 + 64 + lg * 16) ^ swz));
      o[dt] = __builtin_amdgcn_mfma_f32_16x16x32_bf16(pf0, vf0, o[dt], 0, 0, 0);
      o[dt] = __builtin_amdgcn_mfma_f32_16x16x32_bf16(pf1, vf1, o[dt], 0, 0, 0);
    }
    __builtin_amdgcn_s_setprio(0);
    c ^= 1;
  }
  float inv[4];
#pragma unroll
  for (int j = 0; j < 4; ++j) inv[j] = 1.0f / lrow[j];
#pragma unroll
  for (int dt = 0; dt < 8; ++dt)
#pragma unroll
    for (int j = 0; j < 4; ++j) {
      size_t addr = (bL + qs + lg * 4 + j) * QW + h * HD + dt * 16 + lr;
      QKV[addr] = f32_bf16(o[dt][j] * inv[j]);
    }
}

extern "C" void kernel_launch(void* const* d_in, const int* in_sizes, int n_in,
                              void* d_out, int out_size, void* d_ws, size_t ws_size,
                              hipStream_t stream) {
  const float* x  = (const float*)d_in[0];
  const float* Wq = (const float*)d_in[1];
  const float* Wk = (const float*)d_in[2];
  const float* Wv = (const float*)d_in[3];
  const float* Wo = (const float*)d_in[4];
  char* ws = (char*)d_ws;
  // Workspace layout (total 105,906,176 B). If the harness workspace is too
  // small, bail out cleanly (validation fails loudly instead of GPU faulting).
  if (ws_size < 105906176u) return;
  u16* xb    = (u16*)(ws);                    // 8192*2048*2 = 33554432
  u16* Wqkv  = (u16*)(ws + 33554432);         // 3072*2048*2 = 12582912
  u16* Wob   = (u16*)(ws + 46137344);         // 2048*2048*2 =  8388608
  u16* QKV   = (u16*)(ws + 54525952);         // 8192*3072*2 = 50331648
  float* cs  = (float*)(ws + 104857600);      // 131072*4    =   524288
  float* sn  = (float*)(ws + 105381888);      // total end 105906176 B

  // bf16 casts (weights packed: Wq rows 0..2047 | Wk rows 2048..2559 | Wv rows 2560..3071)
  k_cast<<<8192, 256, 0, stream>>>(x, xb, 16777216 / 8);
  k_cast<<<2048, 256, 0, stream>>>(Wq, Wqkv, 4194304 / 8);
  k_cast<<<512, 256, 0, stream>>>(Wk, Wqkv + 2048 * 2048, 1048576 / 8);
  k_cast<<<512, 256, 0, stream>>>(Wv, Wqkv + 2560 * 2048, 1048576 / 8);
  k_cast<<<2048, 256, 0, stream>>>(Wo, Wob, 4194304 / 8);
  k_rope_table<<<512, 256, 0, stream>>>(cs, sn);
  // fused QKV projection: [Q|K|V] = xb @ Wqkv^T
  k_gemm_bt<0><<<dim3(64, 24), 256, 0, stream>>>(xb, 2048, Wqkv, 2048, QKV, QW, 2048);
  // RoPE in place on Q and K regions
  k_rope_apply<<<40960, 256, 0, stream>>>(QKV, cs, sn);
  // flash attention; Z overwrites Q region of QKV
  k_attn<<<dim3(16, 16, 4), 512, 0, stream>>>(QKV);
  // out = Z @ Wo^T (fp32 out)
  k_gemm_bt<1><<<dim3(64, 16), 256, 0, stream>>>(QKV, QW, Wob, 2048, d_out, 2048, 2048);
}

// Round 8
// 531.126 us; speedup vs baseline: 1.4620x; 1.4620x over previous
//
#include <hip/hip_runtime.h>
#include <hip/hip_bf16.h>
#include <math.h>

typedef unsigned short u16;
typedef unsigned int u32;
typedef __attribute__((ext_vector_type(8))) short short8;
typedef __attribute__((ext_vector_type(8))) u16 ushort8;
typedef __attribute__((ext_vector_type(4))) float f32x4;

#define N_B 4
#define L_S 2048
#define E_D 2048
#define NH 16
#define HD 128
#define WIN 1024
#define QW 3072  // QKV buffer row width: 2048 q | 512 k | 512 v
#define LOG2E 1.4426950408889634f

static __device__ __forceinline__ u16 f32_bf16(float f) {
  u32 u = __builtin_bit_cast(u32, f);
  u = (u + 0x7fffu + ((u >> 16) & 1u)) >> 16;  // RNE
  return (u16)u;
}
static __device__ __forceinline__ float bf16_f32(u16 h) {
  u32 u = ((u32)h) << 16;
  return __builtin_bit_cast(float, u);
}
static __device__ __forceinline__ void gload_lds16(const void* g, void* l) {
  __builtin_amdgcn_global_load_lds((__attribute__((address_space(1))) void*)g,
                                   (__attribute__((address_space(3))) void*)l, 16, 0, 0);
}

// ---------------- fp32 -> bf16 cast (n multiple of 8) ----------------
__global__ void k_cast(const float* __restrict__ src, u16* __restrict__ dst, int n8) {
  int i = blockIdx.x * blockDim.x + threadIdx.x;
  if (i >= n8) return;
  const float4* s = (const float4*)src + (size_t)i * 2;
  float4 a = s[0], b = s[1];
  ushort8 v;
  v[0] = f32_bf16(a.x); v[1] = f32_bf16(a.y); v[2] = f32_bf16(a.z); v[3] = f32_bf16(a.w);
  v[4] = f32_bf16(b.x); v[5] = f32_bf16(b.y); v[6] = f32_bf16(b.z); v[7] = f32_bf16(b.w);
  *((ushort8*)dst + i) = v;
}

// ---------------- RoPE cos/sin table: [L][64] ----------------
__global__ void k_rope_table(float* __restrict__ cs, float* __restrict__ sn) {
  int idx = blockIdx.x * blockDim.x + threadIdx.x;  // 2048*64
  int l = idx >> 6, f = idx & 63;
  float freq = exp2f(-(float)f * (13.287712379549449f / 64.0f));  // 10000^(-2f/128)
  float ang = (float)l * freq;
  cs[idx] = cosf(ang);
  sn[idx] = sinf(ang);
}

// ---------------- interleaved RoPE applied in place to Q and K of QKV ----------------
__global__ void k_rope_apply(u16* __restrict__ QKV, const float* __restrict__ cs,
                             const float* __restrict__ sn) {
  int idx = blockIdx.x * blockDim.x + threadIdx.x;  // 8192*20*64 exactly
  int f = idx & 63;
  int rest = idx >> 6;
  int hh = rest % 20;          // 0..15 q heads, 16..19 kv heads
  int row = rest / 20;         // 0..8191 (= n*L + l)
  int l = row & (L_S - 1);
  int col = (hh < NH) ? (hh * HD + 2 * f) : (E_D + (hh - NH) * HD + 2 * f);
  u32* p = (u32*)(QKV + (size_t)row * QW + col);
  u32 v = *p;
  float xr = bf16_f32((u16)(v & 0xffffu));
  float xi = bf16_f32((u16)(v >> 16));
  float c = cs[l * 64 + f], s = sn[l * 64 + f];
  float orr = xr * c - xi * s;
  float oii = xr * s + xi * c;
  *p = (u32)f32_bf16(orr) | ((u32)f32_bf16(oii) << 16);
}

// ---------------- C = A @ B^T, bf16 in, bf16 or f32 out ----------------
// A: MxK row-major (lda), B: NxK row-major (ldb). 128x128 tile, BK=64, 4 waves.
// XCD-aware block swizzle (T1): nwg%8==0 for both launches -> bijective.
template <int OUT_F32>
__global__ __launch_bounds__(256) void k_gemm_bt(
    const u16* __restrict__ A, int lda,
    const u16* __restrict__ B, int ldb,
    void* __restrict__ Cp, int ldc, int K) {
  __shared__ __align__(16) u16 As[128 * 64];
  __shared__ __align__(16) u16 Bs[128 * 64];
  const int tid = threadIdx.x;
  const int lane = tid & 63, w = tid >> 6;
  const int lr = lane & 15, lg = lane >> 4;
  const int gx = gridDim.x, nwg = gx * gridDim.y;
  const int fid = blockIdx.y * gx + blockIdx.x;
  const int cpx = nwg >> 3;
  const int sid = (fid & 7) * cpx + (fid >> 3);
  const int m0 = (sid % gx) * 128, n0 = (sid / gx) * 128;
  const int wm = (w >> 1) * 64, wn = (w & 1) * 64;
  const int srow = tid >> 3, scol = (tid & 7) * 8;  // staging: 16B per lane
  const f32x4 z4 = {0.f, 0.f, 0.f, 0.f};
  f32x4 acc[4][4];
#pragma unroll
  for (int i = 0; i < 4; ++i)
#pragma unroll
    for (int j = 0; j < 4; ++j) acc[i][j] = z4;
  for (int kt = 0; kt < K; kt += 64) {
#pragma unroll
    for (int rr = 0; rr < 4; ++rr) {
      gload_lds16(A + (size_t)(m0 + rr * 32 + srow) * lda + kt + scol,
                  (char*)As + rr * 4096 + w * 1024);
      gload_lds16(B + (size_t)(n0 + rr * 32 + srow) * ldb + kt + scol,
                  (char*)Bs + rr * 4096 + w * 1024);
    }
    __syncthreads();
#pragma unroll
    for (int kk = 0; kk < 64; kk += 32) {
      short8 af[4], bfr[4];
#pragma unroll
      for (int mi = 0; mi < 4; ++mi)
        af[mi] = *(const short8*)(As + (wm + mi * 16 + lr) * 64 + kk + lg * 8);
#pragma unroll
      for (int ni = 0; ni < 4; ++ni)
        bfr[ni] = *(const short8*)(Bs + (wn + ni * 16 + lr) * 64 + kk + lg * 8);
#pragma unroll
      for (int mi = 0; mi < 4; ++mi)
#pragma unroll
        for (int ni = 0; ni < 4; ++ni)
          acc[mi][ni] =
              __builtin_amdgcn_mfma_f32_16x16x32_bf16(af[mi], bfr[ni], acc[mi][ni], 0, 0, 0);
    }
    __syncthreads();
  }
#pragma unroll
  for (int mi = 0; mi < 4; ++mi)
#pragma unroll
    for (int ni = 0; ni < 4; ++ni)
#pragma unroll
      for (int j = 0; j < 4; ++j) {
        size_t r = (size_t)(m0 + wm + mi * 16 + lg * 4 + j);
        int c = n0 + wn + ni * 16 + lr;
        if (OUT_F32)
          ((float*)Cp)[r * ldc + c] = acc[mi][ni][j];
        else
          ((u16*)Cp)[r * ldc + c] = f32_bf16(acc[mi][ni][j]);
      }
}

// ---------------- sliding-window flash attention (pipelined, 8 waves) ----------------
// Grid (L/128, H, N). 8 waves; wave w owns q-rows [qb*128+w*16, +16). KV tile = 64.
// Double-buffered K (global_load_lds, pre-swizzled source) and V (reg-staged,
// swizzled ds_write). One barrier per tile (cross-wave reuse ordering audited).
// __launch_bounds__(512, 2): 2nd arg acts as min BLOCKS/CU on this compiler
// (round-7 evidence: (512,4) -> VGPR capped at 64 -> massive scratch spills).
// 2 blocks/CU matches the 80KB LDS limit and gives a 128-VGPR budget (body ~124).
__global__ __launch_bounds__(512, 2) void k_attn(u16* __restrict__ QKV) {
  const int qb = blockIdx.x, h = blockIdx.y, b = blockIdx.z;
  const int tid = threadIdx.x;
  const int lane = tid & 63, w = tid >> 6;      // 8 waves
  const int lr = lane & 15, lg = lane >> 4;
  const int kh = h >> 2;
  const int qs = qb * 128 + w * 16;
  __shared__ __align__(16) u16 Klds[2][64 * 128];  // [kv][d], swizzled, 2 buffers
  __shared__ __align__(16) u16 Vt[2][128 * 64];    // [d][kv], swizzled, 2 buffers
  __shared__ __align__(16) u16 Plds[8][16 * 64];   // per-wave P, swizzled
  char* Pb = (char*)(&Plds[w][0]);
  const int swz = (lr & 7) << 4;                   // read swizzle (row = *16 + lr)
  const float scale = 0.08838834764831845f;        // 1/sqrt(128)
  const size_t bL = (size_t)b * L_S;
  const size_t rowQ = (bL + qs + lr) * QW + h * HD;
  short8 qf[4];
#pragma unroll
  for (int c = 0; c < 4; ++c) qf[c] = *(const short8*)(QKV + rowQ + c * 32 + lg * 8);
  const f32x4 z4 = {0.f, 0.f, 0.f, 0.f};
  f32x4 o[8];
#pragma unroll
  for (int dt = 0; dt < 8; ++dt) o[dt] = z4;
  float mrow[4], lrow[4];
#pragma unroll
  for (int j = 0; j < 4; ++j) { mrow[j] = -3e38f; lrow[j] = 0.f; }
  int t0 = qb * 128 - (WIN - 1);
  if (t0 < 0) t0 = 0;
  t0 >>= 6;
  const int t1 = 2 * qb + 1;  // == (qb*128+127)>>6
  short8 vreg[2];

  // --- staging helpers (512 threads) ---
  auto ISSUE_K = [&](int t, int buf) {
    char* Kb = (char*)Klds + buf * 16384;
#pragma unroll
    for (int rr = 0; rr < 2; ++rr) {
      int row = rr * 32 + (tid >> 4);              // 0..63
      int colb = ((tid & 15) * 16) ^ ((row & 7) << 4);  // inverse-swizzled source
      gload_lds16(QKV + (bL + t * 64 + row) * QW + E_D + kh * HD + (colb >> 1),
                  Kb + rr * 8192 + w * 1024 + (lane << 4));
    }
  };
  auto LOAD_V = [&](int t) {
#pragma unroll
    for (int rr = 0; rr < 2; ++rr)
      vreg[rr] = *(const short8*)(QKV + (bL + t * 64 + lane) * QW + E_D + 512 + kh * HD +
                                  ((w * 2 + rr) * 8));
  };
  auto WRITE_V = [&](int buf) {
    char* Vb = (char*)Vt + buf * 16384;
#pragma unroll
    for (int rr = 0; rr < 2; ++rr) {
      int db = (w * 2 + rr) * 8;                   // multiple of 8 -> row&7 == e
#pragma unroll
      for (int e = 0; e < 8; ++e)
        *(u16*)(Vb + ((((db + e) * 128) + lane * 2) ^ (e << 4))) = (u16)vreg[rr][e];
    }
  };

  // --- prologue: stage tile t0 ---
  LOAD_V(t0);
  ISSUE_K(t0, 0);
  __syncthreads();          // drains K gloads + V reg loads
  WRITE_V(0);               // Vt[0] visible to all waves after barrier1 of iter t0
  int c = 0;

  for (int t = t0; t <= t1; ++t) {
    const int kv0 = t * 64;
    const int tn = (t < t1) ? t + 1 : t1;
    // prefetch next tile: K -> Klds[c^1] (async), V -> regs. Both fly until barrier1.
    ISSUE_K(tn, c ^ 1);
    LOAD_V(tn);
    // --- S = Q K^T from Klds[c]: 4 col-tiles of 16 ---
    char* Kb = (char*)Klds + c * 16384;
    f32x4 s[4];
#pragma unroll
    for (int tile = 0; tile < 4; ++tile) s[tile] = z4;
#pragma unroll
    for (int tile = 0; tile < 4; ++tile)
#pragma unroll
      for (int cc = 0; cc < 4; ++cc) {
        short8 kf = *(const short8*)(Kb + (((tile * 16 + lr) * 256 + cc * 64 + lg * 16) ^ swz));
        s[tile] = __builtin_amdgcn_mfma_f32_16x16x32_bf16(qf[cc], kf, s[tile], 0, 0, 0);
      }
    // --- online softmax (rows = lg*4+j; cols = kv0 + tile*16 + lr) ---
    float p[4][4], pmax[4];
#pragma unroll
    for (int j = 0; j < 4; ++j) {
      int gr = qs + lg * 4 + j;
      float mx = -3e38f;
#pragma unroll
      for (int tile = 0; tile < 4; ++tile) {
        int g = kv0 + tile * 16 + lr;
        bool a = (g <= gr) && (g > gr - WIN);
        float v = a ? s[tile][j] * scale : -3e38f;
        p[tile][j] = v;
        mx = fmaxf(mx, v);
      }
      mx = fmaxf(mx, __shfl_xor(mx, 1));
      mx = fmaxf(mx, __shfl_xor(mx, 2));
      mx = fmaxf(mx, __shfl_xor(mx, 4));
      mx = fmaxf(mx, __shfl_xor(mx, 8));
      pmax[j] = mx;
    }
    // defer-max (T13): rescale only when some row's max grew by > 8
    bool needr = (pmax[0] > mrow[0] + 8.f) || (pmax[1] > mrow[1] + 8.f) ||
                 (pmax[2] > mrow[2] + 8.f) || (pmax[3] > mrow[3] + 8.f);
    if (__ballot(needr)) {
      float al[4];
#pragma unroll
      for (int j = 0; j < 4; ++j) {
        float mn = fmaxf(mrow[j], pmax[j]);
        al[j] = exp2f((mrow[j] - mn) * LOG2E);
        mrow[j] = mn;
        lrow[j] *= al[j];
      }
#pragma unroll
      for (int dt = 0; dt < 8; ++dt) {
        o[dt][0] *= al[0]; o[dt][1] *= al[1]; o[dt][2] *= al[2]; o[dt][3] *= al[3];
      }
    }
#pragma unroll
    for (int j = 0; j < 4; ++j) {
      float rs = 0.f;
#pragma unroll
      for (int tile = 0; tile < 4; ++tile) {
        float pe = (p[tile][j] > -1e37f) ? exp2f((p[tile][j] - mrow[j]) * LOG2E) : 0.f;
        p[tile][j] = pe;
        rs += pe;
      }
      rs += __shfl_xor(rs, 1);
      rs += __shfl_xor(rs, 2);
      rs += __shfl_xor(rs, 4);
      rs += __shfl_xor(rs, 8);
      lrow[j] += rs;
      int R = lg * 4 + j;
      int rswz = (R & 7) << 4;
#pragma unroll
      for (int tile = 0; tile < 4; ++tile)
        *(u16*)(Pb + ((R * 128 + (tile * 16 + lr) * 2) ^ rswz)) = f32_bf16(p[tile][j]);
    }
    __syncthreads();  // barrier1: drains K(tn)+V(tn); P + Vt[c] visible; orders reuse
    // stage V(tn) into the spare buffer (PV below reads Vt[c], no overlap)
    WRITE_V(c ^ 1);
    // --- O += P V from Vt[c] ---
    char* Vb = (char*)Vt + c * 16384;
    short8 pf0 = *(const short8*)(Pb + ((lr * 128 + 0 + lg * 16) ^ swz));
    short8 pf1 = *(const short8*)(Pb + ((lr * 128 + 64 + lg * 16) ^ swz));
    __builtin_amdgcn_s_setprio(1);
#pragma unroll
    for (int dt = 0; dt < 8; ++dt) {
      short8 vf0 = *(const short8*)(Vb + (((dt * 16 + lr) * 128 + 0 + lg * 16) ^ swz));
      short8 vf1 = *(const short8*)(Vb + (((dt * 16 + lr) * 128 + 64 + lg * 16) ^ swz));
      o[dt] = __builtin_amdgcn_mfma_f32_16x16x32_bf16(pf0, vf0, o[dt], 0, 0, 0);
      o[dt] = __builtin_amdgcn_mfma_f32_16x16x32_bf16(pf1, vf1, o[dt], 0, 0, 0);
    }
    __builtin_amdgcn_s_setprio(0);
    c ^= 1;
  }
  float inv[4];
#pragma unroll
  for (int j = 0; j < 4; ++j) inv[j] = 1.0f / lrow[j];
#pragma unroll
  for (int dt = 0; dt < 8; ++dt)
#pragma unroll
    for (int j = 0; j < 4; ++j) {
      size_t addr = (bL + qs + lg * 4 + j) * QW + h * HD + dt * 16 + lr;
      QKV[addr] = f32_bf16(o[dt][j] * inv[j]);
    }
}

extern "C" void kernel_launch(void* const* d_in, const int* in_sizes, int n_in,
                              void* d_out, int out_size, void* d_ws, size_t ws_size,
                              hipStream_t stream) {
  const float* x  = (const float*)d_in[0];
  const float* Wq = (const float*)d_in[1];
  const float* Wk = (const float*)d_in[2];
  const float* Wv = (const float*)d_in[3];
  const float* Wo = (const float*)d_in[4];
  char* ws = (char*)d_ws;
  // Workspace layout (total 105,906,176 B). If the harness workspace is too
  // small, bail out cleanly (validation fails loudly instead of GPU faulting).
  if (ws_size < 105906176u) return;
  u16* xb    = (u16*)(ws);                    // 8192*2048*2 = 33554432
  u16* Wqkv  = (u16*)(ws + 33554432);         // 3072*2048*2 = 12582912
  u16* Wob   = (u16*)(ws + 46137344);         // 2048*2048*2 =  8388608
  u16* QKV   = (u16*)(ws + 54525952);         // 8192*3072*2 = 50331648
  float* cs  = (float*)(ws + 104857600);      // 131072*4    =   524288
  float* sn  = (float*)(ws + 105381888);      // total end 105906176 B

  // bf16 casts (weights packed: Wq rows 0..2047 | Wk rows 2048..2559 | Wv rows 2560..3071)
  k_cast<<<8192, 256, 0, stream>>>(x, xb, 16777216 / 8);
  k_cast<<<2048, 256, 0, stream>>>(Wq, Wqkv, 4194304 / 8);
  k_cast<<<512, 256, 0, stream>>>(Wk, Wqkv + 2048 * 2048, 1048576 / 8);
  k_cast<<<512, 256, 0, stream>>>(Wv, Wqkv + 2560 * 2048, 1048576 / 8);
  k_cast<<<2048, 256, 0, stream>>>(Wo, Wob, 4194304 / 8);
  k_rope_table<<<512, 256, 0, stream>>>(cs, sn);
  // fused QKV projection: [Q|K|V] = xb @ Wqkv^T
  k_gemm_bt<0><<<dim3(64, 24), 256, 0, stream>>>(xb, 2048, Wqkv, 2048, QKV, QW, 2048);
  // RoPE in place on Q and K regions
  k_rope_apply<<<40960, 256, 0, stream>>>(QKV, cs, sn);
  // flash attention; Z overwrites Q region of QKV
  k_attn<<<dim3(16, 16, 4), 512, 0, stream>>>(QKV);
  // out = Z @ Wo^T (fp32 out)
  k_gemm_bt<1><<<dim3(64, 16), 256, 0, stream>>>(QKV, QW, Wob, 2048, d_out, 2048, 2048);
}

// Round 9
// 527.873 us; speedup vs baseline: 1.4710x; 1.0062x over previous
//
#include <hip/hip_runtime.h>
#include <hip/hip_bf16.h>
#include <math.h>

typedef unsigned short u16;
typedef unsigned int u32;
typedef __attribute__((ext_vector_type(8))) short short8;
typedef __attribute__((ext_vector_type(8))) u16 ushort8;
typedef __attribute__((ext_vector_type(4))) float f32x4;

#define N_B 4
#define L_S 2048
#define E_D 2048
#define NH 16
#define HD 128
#define WIN 1024
#define QW 3072  // QKV buffer row width: 2048 q | 512 k | 512 v
#define LOG2E 1.4426950408889634f

static __device__ __forceinline__ u16 f32_bf16(float f) {
  u32 u = __builtin_bit_cast(u32, f);
  u = (u + 0x7fffu + ((u >> 16) & 1u)) >> 16;  // RNE
  return (u16)u;
}
static __device__ __forceinline__ float bf16_f32(u16 h) {
  u32 u = ((u32)h) << 16;
  return __builtin_bit_cast(float, u);
}
static __device__ __forceinline__ void gload_lds16(const void* g, void* l) {
  __builtin_amdgcn_global_load_lds((__attribute__((address_space(1))) void*)g,
                                   (__attribute__((address_space(3))) void*)l, 16, 0, 0);
}

// ---------------- fp32 -> bf16 cast (n multiple of 8) ----------------
__global__ void k_cast(const float* __restrict__ src, u16* __restrict__ dst, int n8) {
  int i = blockIdx.x * blockDim.x + threadIdx.x;
  if (i >= n8) return;
  const float4* s = (const float4*)src + (size_t)i * 2;
  float4 a = s[0], b = s[1];
  ushort8 v;
  v[0] = f32_bf16(a.x); v[1] = f32_bf16(a.y); v[2] = f32_bf16(a.z); v[3] = f32_bf16(a.w);
  v[4] = f32_bf16(b.x); v[5] = f32_bf16(b.y); v[6] = f32_bf16(b.z); v[7] = f32_bf16(b.w);
  *((ushort8*)dst + i) = v;
}

// ---------------- RoPE cos/sin table: [L][64] ----------------
__global__ void k_rope_table(float* __restrict__ cs, float* __restrict__ sn) {
  int idx = blockIdx.x * blockDim.x + threadIdx.x;  // 2048*64
  int l = idx >> 6, f = idx & 63;
  float freq = exp2f(-(float)f * (13.287712379549449f / 64.0f));  // 10000^(-2f/128)
  float ang = (float)l * freq;
  cs[idx] = cosf(ang);
  sn[idx] = sinf(ang);
}

// ---------------- interleaved RoPE applied in place to Q and K of QKV ----------------
__global__ void k_rope_apply(u16* __restrict__ QKV, const float* __restrict__ cs,
                             const float* __restrict__ sn) {
  int idx = blockIdx.x * blockDim.x + threadIdx.x;  // 8192*20*64 exactly
  int f = idx & 63;
  int rest = idx >> 6;
  int hh = rest % 20;          // 0..15 q heads, 16..19 kv heads
  int row = rest / 20;         // 0..8191 (= n*L + l)
  int l = row & (L_S - 1);
  int col = (hh < NH) ? (hh * HD + 2 * f) : (E_D + (hh - NH) * HD + 2 * f);
  u32* p = (u32*)(QKV + (size_t)row * QW + col);
  u32 v = *p;
  float xr = bf16_f32((u16)(v & 0xffffu));
  float xi = bf16_f32((u16)(v >> 16));
  float c = cs[l * 64 + f], s = sn[l * 64 + f];
  float orr = xr * c - xi * s;
  float oii = xr * s + xi * c;
  *p = (u32)f32_bf16(orr) | ((u32)f32_bf16(oii) << 16);
}

// ---------------- C = A @ B^T, bf16 in, bf16 or f32 out ----------------
// A: MxK row-major (lda), B: NxK row-major (ldb). 128x128 tile, BK=64, 4 waves.
// XCD-aware block swizzle (T1): nwg%8==0 for both launches -> bijective.
template <int OUT_F32>
__global__ __launch_bounds__(256) void k_gemm_bt(
    const u16* __restrict__ A, int lda,
    const u16* __restrict__ B, int ldb,
    void* __restrict__ Cp, int ldc, int K) {
  __shared__ __align__(16) u16 As[128 * 64];
  __shared__ __align__(16) u16 Bs[128 * 64];
  const int tid = threadIdx.x;
  const int lane = tid & 63, w = tid >> 6;
  const int lr = lane & 15, lg = lane >> 4;
  const int gx = gridDim.x, nwg = gx * gridDim.y;
  const int fid = blockIdx.y * gx + blockIdx.x;
  const int cpx = nwg >> 3;
  const int sid = (fid & 7) * cpx + (fid >> 3);
  const int m0 = (sid % gx) * 128, n0 = (sid / gx) * 128;
  const int wm = (w >> 1) * 64, wn = (w & 1) * 64;
  const int srow = tid >> 3, scol = (tid & 7) * 8;  // staging: 16B per lane
  const f32x4 z4 = {0.f, 0.f, 0.f, 0.f};
  f32x4 acc[4][4];
#pragma unroll
  for (int i = 0; i < 4; ++i)
#pragma unroll
    for (int j = 0; j < 4; ++j) acc[i][j] = z4;
  for (int kt = 0; kt < K; kt += 64) {
#pragma unroll
    for (int rr = 0; rr < 4; ++rr) {
      gload_lds16(A + (size_t)(m0 + rr * 32 + srow) * lda + kt + scol,
                  (char*)As + rr * 4096 + w * 1024);
      gload_lds16(B + (size_t)(n0 + rr * 32 + srow) * ldb + kt + scol,
                  (char*)Bs + rr * 4096 + w * 1024);
    }
    __syncthreads();
#pragma unroll
    for (int kk = 0; kk < 64; kk += 32) {
      short8 af[4], bfr[4];
#pragma unroll
      for (int mi = 0; mi < 4; ++mi)
        af[mi] = *(const short8*)(As + (wm + mi * 16 + lr) * 64 + kk + lg * 8);
#pragma unroll
      for (int ni = 0; ni < 4; ++ni)
        bfr[ni] = *(const short8*)(Bs + (wn + ni * 16 + lr) * 64 + kk + lg * 8);
#pragma unroll
      for (int mi = 0; mi < 4; ++mi)
#pragma unroll
        for (int ni = 0; ni < 4; ++ni)
          acc[mi][ni] =
              __builtin_amdgcn_mfma_f32_16x16x32_bf16(af[mi], bfr[ni], acc[mi][ni], 0, 0, 0);
    }
    __syncthreads();
  }
#pragma unroll
  for (int mi = 0; mi < 4; ++mi)
#pragma unroll
    for (int ni = 0; ni < 4; ++ni)
#pragma unroll
      for (int j = 0; j < 4; ++j) {
        size_t r = (size_t)(m0 + wm + mi * 16 + lg * 4 + j);
        int c = n0 + wn + ni * 16 + lr;
        if (OUT_F32)
          ((float*)Cp)[r * ldc + c] = acc[mi][ni][j];
        else
          ((u16*)Cp)[r * ldc + c] = f32_bf16(acc[mi][ni][j]);
      }
}

// ---------------- sliding-window flash attention (pipelined, 8 waves) ----------------
// Grid (L/128, H, N). 8 waves; wave w owns q-rows [qb*128+w*16, +16). KV tile = 64.
// K double-buffered (global_load_lds, pre-swizzled source); V single-buffered
// (reg-staged: vreg carries tile t+1 across the iteration, LDS image rewritten
// after barrier2). LDS = 32K(K) + 16K(V) + 16K(P) = 64 KB -> 2 blocks/CU
// (round-8 lesson: 80 KB -> 1 block/CU, occupancy stuck at 17%).
// __launch_bounds__(512, 2): 2nd arg acts as min BLOCKS/CU on this compiler
// (round-7 evidence: (512,4) -> VGPR capped at 64 -> massive scratch spills).
__global__ __launch_bounds__(512, 2) void k_attn(u16* __restrict__ QKV) {
  const int qb = blockIdx.x, h = blockIdx.y, b = blockIdx.z;
  const int tid = threadIdx.x;
  const int lane = tid & 63, w = tid >> 6;      // 8 waves
  const int lr = lane & 15, lg = lane >> 4;
  const int kh = h >> 2;
  const int qs = qb * 128 + w * 16;
  __shared__ __align__(16) u16 Klds[2][64 * 128];  // [kv][d], swizzled, 2 buffers
  __shared__ __align__(16) u16 Vt[128 * 64];       // [d][kv], swizzled, 1 buffer
  __shared__ __align__(16) u16 Plds[8][16 * 64];   // per-wave P, swizzled
  char* Pb = (char*)(&Plds[w][0]);
  char* Vb = (char*)Vt;
  const int swz = (lr & 7) << 4;                   // read swizzle (row = *16 + lr)
  const float scale = 0.08838834764831845f;        // 1/sqrt(128)
  const size_t bL = (size_t)b * L_S;
  const size_t rowQ = (bL + qs + lr) * QW + h * HD;
  short8 qf[4];
#pragma unroll
  for (int c = 0; c < 4; ++c) qf[c] = *(const short8*)(QKV + rowQ + c * 32 + lg * 8);
  const f32x4 z4 = {0.f, 0.f, 0.f, 0.f};
  f32x4 o[8];
#pragma unroll
  for (int dt = 0; dt < 8; ++dt) o[dt] = z4;
  float mrow[4], lrow[4];
#pragma unroll
  for (int j = 0; j < 4; ++j) { mrow[j] = -3e38f; lrow[j] = 0.f; }
  int t0 = qb * 128 - (WIN - 1);
  if (t0 < 0) t0 = 0;
  t0 >>= 6;
  const int t1 = 2 * qb + 1;  // == (qb*128+127)>>6
  short8 vreg[2];

  // --- staging helpers (512 threads) ---
  auto ISSUE_K = [&](int t, int buf) {
    char* Kb = (char*)Klds + buf * 16384;
#pragma unroll
    for (int rr = 0; rr < 2; ++rr) {
      int row = rr * 32 + (tid >> 4);              // 0..63
      int colb = ((tid & 15) * 16) ^ ((row & 7) << 4);  // inverse-swizzled source
      gload_lds16(QKV + (bL + t * 64 + row) * QW + E_D + kh * HD + (colb >> 1),
                  Kb + rr * 8192 + w * 1024 + (lane << 4));
    }
  };
  auto LOAD_V = [&](int t) {
#pragma unroll
    for (int rr = 0; rr < 2; ++rr)
      vreg[rr] = *(const short8*)(QKV + (bL + t * 64 + lane) * QW + E_D + 512 + kh * HD +
                                  ((w * 2 + rr) * 8));
  };
  auto WRITE_V = [&]() {
#pragma unroll
    for (int rr = 0; rr < 2; ++rr) {
      int db = (w * 2 + rr) * 8;                   // multiple of 8 -> row&7 == e
#pragma unroll
      for (int e = 0; e < 8; ++e)
        *(u16*)(Vb + ((((db + e) * 128) + lane * 2) ^ (e << 4))) = (u16)vreg[rr][e];
    }
  };

  // --- prologue: stage tile t0 ---
  LOAD_V(t0);
  ISSUE_K(t0, 0);
  __syncthreads();          // drains K gloads + V reg loads
  WRITE_V();                // Vt holds tile t0; visible at barrier1 of iter t0
  int c = 0;

  for (int t = t0; t <= t1; ++t) {
    const int kv0 = t * 64;
    const int tn = (t < t1) ? t + 1 : t1;
    // prefetch next tile: K -> Klds[c^1] (async), V -> regs. Both fly until barrier1.
    ISSUE_K(tn, c ^ 1);
    LOAD_V(tn);
    // --- S = Q K^T from Klds[c]: 4 col-tiles of 16 ---
    char* Kb = (char*)Klds + c * 16384;
    f32x4 s[4];
#pragma unroll
    for (int tile = 0; tile < 4; ++tile) s[tile] = z4;
#pragma unroll
    for (int tile = 0; tile < 4; ++tile)
#pragma unroll
      for (int cc = 0; cc < 4; ++cc) {
        short8 kf = *(const short8*)(Kb + (((tile * 16 + lr) * 256 + cc * 64 + lg * 16) ^ swz));
        s[tile] = __builtin_amdgcn_mfma_f32_16x16x32_bf16(qf[cc], kf, s[tile], 0, 0, 0);
      }
    // --- online softmax (rows = lg*4+j; cols = kv0 + tile*16 + lr) ---
    float p[4][4], pmax[4];
#pragma unroll
    for (int j = 0; j < 4; ++j) {
      int gr = qs + lg * 4 + j;
      float mx = -3e38f;
#pragma unroll
      for (int tile = 0; tile < 4; ++tile) {
        int g = kv0 + tile * 16 + lr;
        bool a = (g <= gr) && (g > gr - WIN);
        float v = a ? s[tile][j] * scale : -3e38f;
        p[tile][j] = v;
        mx = fmaxf(mx, v);
      }
      mx = fmaxf(mx, __shfl_xor(mx, 1));
      mx = fmaxf(mx, __shfl_xor(mx, 2));
      mx = fmaxf(mx, __shfl_xor(mx, 4));
      mx = fmaxf(mx, __shfl_xor(mx, 8));
      pmax[j] = mx;
    }
    // defer-max (T13): rescale only when some row's max grew by > 8
    bool needr = (pmax[0] > mrow[0] + 8.f) || (pmax[1] > mrow[1] + 8.f) ||
                 (pmax[2] > mrow[2] + 8.f) || (pmax[3] > mrow[3] + 8.f);
    if (__ballot(needr)) {
      float al[4];
#pragma unroll
      for (int j = 0; j < 4; ++j) {
        float mn = fmaxf(mrow[j], pmax[j]);
        al[j] = exp2f((mrow[j] - mn) * LOG2E);
        mrow[j] = mn;
        lrow[j] *= al[j];
      }
#pragma unroll
      for (int dt = 0; dt < 8; ++dt) {
        o[dt][0] *= al[0]; o[dt][1] *= al[1]; o[dt][2] *= al[2]; o[dt][3] *= al[3];
      }
    }
#pragma unroll
    for (int j = 0; j < 4; ++j) {
      float rs = 0.f;
#pragma unroll
      for (int tile = 0; tile < 4; ++tile) {
        float pe = (p[tile][j] > -1e37f) ? exp2f((p[tile][j] - mrow[j]) * LOG2E) : 0.f;
        p[tile][j] = pe;
        rs += pe;
      }
      rs += __shfl_xor(rs, 1);
      rs += __shfl_xor(rs, 2);
      rs += __shfl_xor(rs, 4);
      rs += __shfl_xor(rs, 8);
      lrow[j] += rs;
      int R = lg * 4 + j;
      int rswz = (R & 7) << 4;
#pragma unroll
      for (int tile = 0; tile < 4; ++tile)
        *(u16*)(Pb + ((R * 128 + (tile * 16 + lr) * 2) ^ rswz)) = f32_bf16(p[tile][j]);
    }
    __syncthreads();  // barrier1: drains K(tn)+V(tn) loads; P + Vt(current) visible
    // --- O += P V from Vt ---
    short8 pf0 = *(const short8*)(Pb + ((lr * 128 + 0 + lg * 16) ^ swz));
    short8 pf1 = *(const short8*)(Pb + ((lr * 128 + 64 + lg * 16) ^ swz));
    __builtin_amdgcn_s_setprio(1);
#pragma unroll
    for (int dt = 0; dt < 8; ++dt) {
      short8 vf0 = *(const short8*)(Vb + (((dt * 16 + lr) * 128 + 0 + lg * 16) ^ swz));
      short8 vf1 = *(const short8*)(Vb + (((dt * 16 + lr) * 128 + 64 + lg * 16) ^ swz));
      o[dt] = __builtin_amdgcn_mfma_f32_16x16x32_bf16(pf0, vf0, o[dt], 0, 0, 0);
      o[dt] = __builtin_amdgcn_mfma_f32_16x16x32_bf16(pf1, vf1, o[dt], 0, 0, 0);
    }
    __builtin_amdgcn_s_setprio(0);
    __syncthreads();  // barrier2: all PV reads of Vt done -> safe to overwrite
    WRITE_V();        // stage V(tn); visible to PV(t+1) via barrier1(t+1)
    c ^= 1;
  }
  float inv[4];
#pragma unroll
  for (int j = 0; j < 4; ++j) inv[j] = 1.0f / lrow[j];
#pragma unroll
  for (int dt = 0; dt < 8; ++dt)
#pragma unroll
    for (int j = 0; j < 4; ++j) {
      size_t addr = (bL + qs + lg * 4 + j) * QW + h * HD + dt * 16 + lr;
      QKV[addr] = f32_bf16(o[dt][j] * inv[j]);
    }
}

extern "C" void kernel_launch(void* const* d_in, const int* in_sizes, int n_in,
                              void* d_out, int out_size, void* d_ws, size_t ws_size,
                              hipStream_t stream) {
  const float* x  = (const float*)d_in[0];
  const float* Wq = (const float*)d_in[1];
  const float* Wk = (const float*)d_in[2];
  const float* Wv = (const float*)d_in[3];
  const float* Wo = (const float*)d_in[4];
  char* ws = (char*)d_ws;
  // Workspace layout (total 105,906,176 B). If the harness workspace is too
  // small, bail out cleanly (validation fails loudly instead of GPU faulting).
  if (ws_size < 105906176u) return;
  u16* xb    = (u16*)(ws);                    // 8192*2048*2 = 33554432
  u16* Wqkv  = (u16*)(ws + 33554432);         // 3072*2048*2 = 12582912
  u16* Wob   = (u16*)(ws + 46137344);         // 2048*2048*2 =  8388608
  u16* QKV   = (u16*)(ws + 54525952);         // 8192*3072*2 = 50331648
  float* cs  = (float*)(ws + 104857600);      // 131072*4    =   524288
  float* sn  = (float*)(ws + 105381888);      // total end 105906176 B

  // bf16 casts (weights packed: Wq rows 0..2047 | Wk rows 2048..2559 | Wv rows 2560..3071)
  k_cast<<<8192, 256, 0, stream>>>(x, xb, 16777216 / 8);
  k_cast<<<2048, 256, 0, stream>>>(Wq, Wqkv, 4194304 / 8);
  k_cast<<<512, 256, 0, stream>>>(Wk, Wqkv + 2048 * 2048, 1048576 / 8);
  k_cast<<<512, 256, 0, stream>>>(Wv, Wqkv + 2560 * 2048, 1048576 / 8);
  k_cast<<<2048, 256, 0, stream>>>(Wo, Wob, 4194304 / 8);
  k_rope_table<<<512, 256, 0, stream>>>(cs, sn);
  // fused QKV projection: [Q|K|V] = xb @ Wqkv^T
  k_gemm_bt<0><<<dim3(64, 24), 256, 0, stream>>>(xb, 2048, Wqkv, 2048, QKV, QW, 2048);
  // RoPE in place on Q and K regions
  k_rope_apply<<<40960, 256, 0, stream>>>(QKV, cs, sn);
  // flash attention; Z overwrites Q region of QKV
  k_attn<<<dim3(16, 16, 4), 512, 0, stream>>>(QKV);
  // out = Z @ Wo^T (fp32 out)
  k_gemm_bt<1><<<dim3(64, 16), 256, 0, stream>>>(QKV, QW, Wob, 2048, d_out, 2048, 2048);
}

// Round 11
// 503.305 us; speedup vs baseline: 1.5428x; 1.0488x over previous
//
#include <hip/hip_runtime.h>
#include <hip/hip_bf16.h>
#include <math.h>

typedef unsigned short u16;
typedef unsigned int u32;
typedef __attribute__((ext_vector_type(8))) short short8;
typedef __attribute__((ext_vector_type(8))) u16 ushort8;
typedef __attribute__((ext_vector_type(4))) float f32x4;

#define N_B 4
#define L_S 2048
#define E_D 2048
#define NH 16
#define HD 128
#define WIN 1024
#define QW 3072  // QKV buffer row width: 2048 q | 512 k | 512 v
#define LOG2E 1.4426950408889634f

static __device__ __forceinline__ u16 f32_bf16(float f) {
  u32 u = __builtin_bit_cast(u32, f);
  u = (u + 0x7fffu + ((u >> 16) & 1u)) >> 16;  // RNE
  return (u16)u;
}
static __device__ __forceinline__ float bf16_f32(u16 h) {
  u32 u = ((u32)h) << 16;
  return __builtin_bit_cast(float, u);
}
static __device__ __forceinline__ void gload_lds16(const void* g, void* l) {
  __builtin_amdgcn_global_load_lds((__attribute__((address_space(1))) void*)g,
                                   (__attribute__((address_space(3))) void*)l, 16, 0, 0);
}

// ---------------- fp32 -> bf16 cast (n multiple of 8) ----------------
__global__ void k_cast(const float* __restrict__ src, u16* __restrict__ dst, int n8) {
  int i = blockIdx.x * blockDim.x + threadIdx.x;
  if (i >= n8) return;
  const float4* s = (const float4*)src + (size_t)i * 2;
  float4 a = s[0], b = s[1];
  ushort8 v;
  v[0] = f32_bf16(a.x); v[1] = f32_bf16(a.y); v[2] = f32_bf16(a.z); v[3] = f32_bf16(a.w);
  v[4] = f32_bf16(b.x); v[5] = f32_bf16(b.y); v[6] = f32_bf16(b.z); v[7] = f32_bf16(b.w);
  *((ushort8*)dst + i) = v;
}

// ---------------- RoPE cos/sin table: [L][64] ----------------
__global__ void k_rope_table(float* __restrict__ cs, float* __restrict__ sn) {
  int idx = blockIdx.x * blockDim.x + threadIdx.x;  // 2048*64
  int l = idx >> 6, f = idx & 63;
  float freq = exp2f(-(float)f * (13.287712379549449f / 64.0f));  // 10000^(-2f/128)
  float ang = (float)l * freq;
  cs[idx] = cosf(ang);
  sn[idx] = sinf(ang);
}

// ---------------- interleaved RoPE applied in place to Q and K of QKV ----------------
__global__ void k_rope_apply(u16* __restrict__ QKV, const float* __restrict__ cs,
                             const float* __restrict__ sn) {
  int idx = blockIdx.x * blockDim.x + threadIdx.x;  // 8192*20*64 exactly
  int f = idx & 63;
  int rest = idx >> 6;
  int hh = rest % 20;          // 0..15 q heads, 16..19 kv heads
  int row = rest / 20;         // 0..8191 (= n*L + l)
  int l = row & (L_S - 1);
  int col = (hh < NH) ? (hh * HD + 2 * f) : (E_D + (hh - NH) * HD + 2 * f);
  u32* p = (u32*)(QKV + (size_t)row * QW + col);
  u32 v = *p;
  float xr = bf16_f32((u16)(v & 0xffffu));
  float xi = bf16_f32((u16)(v >> 16));
  float c = cs[l * 64 + f], s = sn[l * 64 + f];
  float orr = xr * c - xi * s;
  float oii = xr * s + xi * c;
  *p = (u32)f32_bf16(orr) | ((u32)f32_bf16(oii) << 16);
}

// ---------------- C = A @ B^T, bf16 in, bf16 or f32 out ----------------
// A: MxK row-major (lda), B: NxK row-major (ldb). 128x128 tile, BK=64, 4 waves.
// XCD-aware block swizzle (T1): nwg%8==0 for both launches -> bijective.
template <int OUT_F32>
__global__ __launch_bounds__(256) void k_gemm_bt(
    const u16* __restrict__ A, int lda,
    const u16* __restrict__ B, int ldb,
    void* __restrict__ Cp, int ldc, int K) {
  __shared__ __align__(16) u16 As[128 * 64];
  __shared__ __align__(16) u16 Bs[128 * 64];
  const int tid = threadIdx.x;
  const int lane = tid & 63, w = tid >> 6;
  const int lr = lane & 15, lg = lane >> 4;
  const int gx = gridDim.x, nwg = gx * gridDim.y;
  const int fid = blockIdx.y * gx + blockIdx.x;
  const int cpx = nwg >> 3;
  const int sid = (fid & 7) * cpx + (fid >> 3);
  const int m0 = (sid % gx) * 128, n0 = (sid / gx) * 128;
  const int wm = (w >> 1) * 64, wn = (w & 1) * 64;
  const int srow = tid >> 3, scol = (tid & 7) * 8;  // staging: 16B per lane
  const f32x4 z4 = {0.f, 0.f, 0.f, 0.f};
  f32x4 acc[4][4];
#pragma unroll
  for (int i = 0; i < 4; ++i)
#pragma unroll
    for (int j = 0; j < 4; ++j) acc[i][j] = z4;
  for (int kt = 0; kt < K; kt += 64) {
#pragma unroll
    for (int rr = 0; rr < 4; ++rr) {
      gload_lds16(A + (size_t)(m0 + rr * 32 + srow) * lda + kt + scol,
                  (char*)As + rr * 4096 + w * 1024);
      gload_lds16(B + (size_t)(n0 + rr * 32 + srow) * ldb + kt + scol,
                  (char*)Bs + rr * 4096 + w * 1024);
    }
    __syncthreads();
#pragma unroll
    for (int kk = 0; kk < 64; kk += 32) {
      short8 af[4], bfr[4];
#pragma unroll
      for (int mi = 0; mi < 4; ++mi)
        af[mi] = *(const short8*)(As + (wm + mi * 16 + lr) * 64 + kk + lg * 8);
#pragma unroll
      for (int ni = 0; ni < 4; ++ni)
        bfr[ni] = *(const short8*)(Bs + (wn + ni * 16 + lr) * 64 + kk + lg * 8);
#pragma unroll
      for (int mi = 0; mi < 4; ++mi)
#pragma unroll
        for (int ni = 0; ni < 4; ++ni)
          acc[mi][ni] =
              __builtin_amdgcn_mfma_f32_16x16x32_bf16(af[mi], bfr[ni], acc[mi][ni], 0, 0, 0);
    }
    __syncthreads();
  }
#pragma unroll
  for (int mi = 0; mi < 4; ++mi)
#pragma unroll
    for (int ni = 0; ni < 4; ++ni)
#pragma unroll
      for (int j = 0; j < 4; ++j) {
        size_t r = (size_t)(m0 + wm + mi * 16 + lg * 4 + j);
        int c = n0 + wn + ni * 16 + lr;
        if (OUT_F32)
          ((float*)Cp)[r * ldc + c] = acc[mi][ni][j];
        else
          ((u16*)Cp)[r * ldc + c] = f32_bf16(acc[mi][ni][j]);
      }
}

// ---------------- sliding-window flash attention (pipelined, 8 waves) ----------------
// Grid (L/128, H, N). 8 waves; wave w owns q-rows [qb*128+w*16, +16). KV tile = 64.
// SWAPPED QK^T: s = mfma(K_frag, Q_frag) -> C[k][q], so each lane owns ONE q-row
// (q = qs + lane&15) and 16 k-values -> softmax reduce is a local VALU tree +
// 2 shfl_xor (vs 32 serial shfls in the row-spread layout). m/l are per-lane
// scalars in log2 domain. P goes through the same wave-private swizzled LDS.
// K double-buffered (global_load_lds, pre-swizzled source); V single-buffered
// (reg-staged). LDS = 32K(K) + 16K(V) + 16K(P) = 64 KB.
// __launch_bounds__(512, 2): 2nd arg acts as min BLOCKS/CU on this compiler
// (round-7 evidence: (512,4) -> VGPR capped at 64 -> massive scratch spills).
__global__ __launch_bounds__(512, 2) void k_attn(u16* __restrict__ QKV) {
  const int qb = blockIdx.x, h = blockIdx.y, b = blockIdx.z;
  const int tid = threadIdx.x;
  const int lane = tid & 63, w = tid >> 6;      // 8 waves
  const int lr = lane & 15, lg = lane >> 4;
  const int kh = h >> 2;
  const int qs = qb * 128 + w * 16;
  __shared__ __align__(16) u16 Klds[2][64 * 128];  // [kv][d], swizzled, 2 buffers
  __shared__ __align__(16) u16 Vt[128 * 64];       // [d][kv], swizzled, 1 buffer
  __shared__ __align__(16) u16 Plds[8][16 * 64];   // per-wave P, swizzled
  char* Pb = (char*)(&Plds[w][0]);
  char* Vb = (char*)Vt;
  const int swz = (lr & 7) << 4;                   // read swizzle (row = *16 + lr)
  const float SCL2 = 0.08838834764831845f * 1.4426950408889634f;  // scale*log2(e)
  const size_t bL = (size_t)b * L_S;
  const size_t rowQ = (bL + qs + lr) * QW + h * HD;
  short8 qf[4];
#pragma unroll
  for (int c = 0; c < 4; ++c) qf[c] = *(const short8*)(QKV + rowQ + c * 32 + lg * 8);
  const f32x4 z4 = {0.f, 0.f, 0.f, 0.f};
  f32x4 o[8];
#pragma unroll
  for (int dt = 0; dt < 8; ++dt) o[dt] = z4;
  float m2 = -3e38f, lsum = 0.f;  // per-lane stats for q = qs + lr (log2 domain)
  int t0 = qb * 128 - (WIN - 1);
  if (t0 < 0) t0 = 0;
  t0 >>= 6;
  const int t1 = 2 * qb + 1;  // == (qb*128+127)>>6
  short8 vreg[2];

  // --- staging helpers (512 threads) ---
  auto ISSUE_K = [&](int t, int buf) {
    char* Kb = (char*)Klds + buf * 16384;
#pragma unroll
    for (int rr = 0; rr < 2; ++rr) {
      int row = rr * 32 + (tid >> 4);              // 0..63
      int colb = ((tid & 15) * 16) ^ ((row & 7) << 4);  // inverse-swizzled source
      gload_lds16(QKV + (bL + t * 64 + row) * QW + E_D + kh * HD + (colb >> 1),
                  Kb + rr * 8192 + w * 1024 + (lane << 4));
    }
  };
  auto LOAD_V = [&](int t) {
#pragma unroll
    for (int rr = 0; rr < 2; ++rr)
      vreg[rr] = *(const short8*)(QKV + (bL + t * 64 + lane) * QW + E_D + 512 + kh * HD +
                                  ((w * 2 + rr) * 8));
  };
  auto WRITE_V = [&]() {
#pragma unroll
    for (int rr = 0; rr < 2; ++rr) {
      int db = (w * 2 + rr) * 8;                   // multiple of 8 -> row&7 == e
#pragma unroll
      for (int e = 0; e < 8; ++e)
        *(u16*)(Vb + ((((db + e) * 128) + lane * 2) ^ (e << 4))) = (u16)vreg[rr][e];
    }
  };

  // --- prologue: stage tile t0 ---
  LOAD_V(t0);
  ISSUE_K(t0, 0);
  __syncthreads();          // drains K gloads + V reg loads
  WRITE_V();                // Vt holds tile t0; visible at barrier1 of iter t0
  int c = 0;

  for (int t = t0; t <= t1; ++t) {
    const int kv0 = t * 64;
    const int tn = (t < t1) ? t + 1 : t1;
    // prefetch next tile: K -> Klds[c^1] (async), V -> regs. Both fly until barrier1.
    ISSUE_K(tn, c ^ 1);
    LOAD_V(tn);
    // --- S^T = K Q^T from Klds[c]: s[tile][j] = S[q = qs+lr][k = kv0+tile*16+lg*4+j] ---
    char* Kb = (char*)Klds + c * 16384;
    f32x4 s[4];
#pragma unroll
    for (int tile = 0; tile < 4; ++tile) s[tile] = z4;
#pragma unroll
    for (int tile = 0; tile < 4; ++tile)
#pragma unroll
      for (int cc = 0; cc < 4; ++cc) {
        short8 kf = *(const short8*)(Kb + (((tile * 16 + lr) * 256 + cc * 64 + lg * 16) ^ swz));
        s[tile] = __builtin_amdgcn_mfma_f32_16x16x32_bf16(kf, qf[cc], s[tile], 0, 0, 0);
      }
    // --- lane-local masked scores in log2 domain ---
    const int q = qs + lr;
    float v[4][4];
#pragma unroll
    for (int t2 = 0; t2 < 4; ++t2)
#pragma unroll
      for (int j = 0; j < 4; ++j) {
        int g = kv0 + t2 * 16 + lg * 4 + j;
        bool a = (g <= q) && (g > q - WIN);
        v[t2][j] = a ? s[t2][j] * SCL2 : -3e38f;
      }
    // local max tree + 2-shfl cross-group reduce (4 lanes per q: lg=0..3)
    float mt0 = fmaxf(fmaxf(v[0][0], v[0][1]), fmaxf(v[0][2], v[0][3]));
    float mt1 = fmaxf(fmaxf(v[1][0], v[1][1]), fmaxf(v[1][2], v[1][3]));
    float mt2 = fmaxf(fmaxf(v[2][0], v[2][1]), fmaxf(v[2][2], v[2][3]));
    float mt3 = fmaxf(fmaxf(v[3][0], v[3][1]), fmaxf(v[3][2], v[3][3]));
    float mx = fmaxf(fmaxf(mt0, mt1), fmaxf(mt2, mt3));
    mx = fmaxf(mx, __shfl_xor(mx, 16));
    mx = fmaxf(mx, __shfl_xor(mx, 32));
    // defer-max (T13): 8 nats = 11.5416 bits; branch is wave-uniform via ballot
    if (__ballot(mx > m2 + 11.5415603f)) {
      float mn = fmaxf(m2, mx);
      float alpha = exp2f(m2 - mn);
      m2 = mn;
      lsum *= alpha;
      float alj[4];
#pragma unroll
      for (int j = 0; j < 4; ++j) alj[j] = __shfl(alpha, lg * 4 + j);
#pragma unroll
      for (int dt = 0; dt < 8; ++dt) {
        o[dt][0] *= alj[0]; o[dt][1] *= alj[1]; o[dt][2] *= alj[2]; o[dt][3] *= alj[3];
      }
    }
    // exp + local sum tree + 2-shfl reduce
#pragma unroll
    for (int t2 = 0; t2 < 4; ++t2)
#pragma unroll
      for (int j = 0; j < 4; ++j)
        v[t2][j] = (v[t2][j] > -1e37f) ? exp2f(v[t2][j] - m2) : 0.f;
    float rs = (((v[0][0] + v[0][1]) + (v[0][2] + v[0][3])) +
                ((v[1][0] + v[1][1]) + (v[1][2] + v[1][3]))) +
               (((v[2][0] + v[2][1]) + (v[2][2] + v[2][3])) +
                ((v[3][0] + v[3][1]) + (v[3][2] + v[3][3])));
    rs += __shfl_xor(rs, 16);
    rs += __shfl_xor(rs, 32);
    lsum += rs;
    // P -> wave-private LDS (row = q = lr, col = k), same swizzle family
#pragma unroll
    for (int t2 = 0; t2 < 4; ++t2)
#pragma unroll
      for (int j = 0; j < 4; ++j)
        *(u16*)(Pb + ((lr * 128 + (t2 * 16 + lg * 4 + j) * 2) ^ swz)) = f32_bf16(v[t2][j]);
    __syncthreads();  // barrier1: drains K(tn)+V(tn) loads; P + Vt(current) visible
    // --- O += P V from Vt ---
    short8 pf0 = *(const short8*)(Pb + ((lr * 128 + 0 + lg * 16) ^ swz));
    short8 pf1 = *(const short8*)(Pb + ((lr * 128 + 64 + lg * 16) ^ swz));
    __builtin_amdgcn_s_setprio(1);
#pragma unroll
    for (int dt = 0; dt < 8; ++dt) {
      short8 vf0 = *(const short8*)(Vb + (((dt * 16 + lr) * 128 + 0 + lg * 16) ^ swz));
      short8 vf1 = *(const short8*)(Vb + (((dt * 16 + lr) * 128 + 64 + lg * 16) ^ swz));
      o[dt] = __builtin_amdgcn_mfma_f32_16x16x32_bf16(pf0, vf0, o[dt], 0, 0, 0);
      o[dt] = __builtin_amdgcn_mfma_f32_16x16x32_bf16(pf1, vf1, o[dt], 0, 0, 0);
    }
    __builtin_amdgcn_s_setprio(0);
    __syncthreads();  // barrier2: all PV reads of Vt done -> safe to overwrite
    WRITE_V();        // stage V(tn); visible to PV(t+1) via barrier1(t+1)
    c ^= 1;
  }
  float inv[4];
#pragma unroll
  for (int j = 0; j < 4; ++j) inv[j] = 1.0f / __shfl(lsum, lg * 4 + j);
#pragma unroll
  for (int dt = 0; dt < 8; ++dt)
#pragma unroll
    for (int j = 0; j < 4; ++j) {
      size_t addr = (bL + qs + lg * 4 + j) * QW + h * HD + dt * 16 + lr;
      QKV[addr] = f32_bf16(o[dt][j] * inv[j]);
    }
}

extern "C" void kernel_launch(void* const* d_in, const int* in_sizes, int n_in,
                              void* d_out, int out_size, void* d_ws, size_t ws_size,
                              hipStream_t stream) {
  const float* x  = (const float*)d_in[0];
  const float* Wq = (const float*)d_in[1];
  const float* Wk = (const float*)d_in[2];
  const float* Wv = (const float*)d_in[3];
  const float* Wo = (const float*)d_in[4];
  char* ws = (char*)d_ws;
  // Workspace layout (total 105,906,176 B). If the harness workspace is too
  // small, bail out cleanly (validation fails loudly instead of GPU faulting).
  if (ws_size < 105906176u) return;
  u16* xb    = (u16*)(ws);                    // 8192*2048*2 = 33554432
  u16* Wqkv  = (u16*)(ws + 33554432);         // 3072*2048*2 = 12582912
  u16* Wob   = (u16*)(ws + 46137344);         // 2048*2048*2 =  8388608
  u16* QKV   = (u16*)(ws + 54525952);         // 8192*3072*2 = 50331648
  float* cs  = (float*)(ws + 104857600);      // 131072*4    =   524288
  float* sn  = (float*)(ws + 105381888);      // total end 105906176 B

  // bf16 casts (weights packed: Wq rows 0..2047 | Wk rows 2048..2559 | Wv rows 2560..3071)
  k_cast<<<8192, 256, 0, stream>>>(x, xb, 16777216 / 8);
  k_cast<<<2048, 256, 0, stream>>>(Wq, Wqkv, 4194304 / 8);
  k_cast<<<512, 256, 0, stream>>>(Wk, Wqkv + 2048 * 2048, 1048576 / 8);
  k_cast<<<512, 256, 0, stream>>>(Wv, Wqkv + 2560 * 2048, 1048576 / 8);
  k_cast<<<2048, 256, 0, stream>>>(Wo, Wob, 4194304 / 8);
  k_rope_table<<<512, 256, 0, stream>>>(cs, sn);
  // fused QKV projection: [Q|K|V] = xb @ Wqkv^T
  k_gemm_bt<0><<<dim3(64, 24), 256, 0, stream>>>(xb, 2048, Wqkv, 2048, QKV, QW, 2048);
  // RoPE in place on Q and K regions
  k_rope_apply<<<40960, 256, 0, stream>>>(QKV, cs, sn);
  // flash attention; Z overwrites Q region of QKV
  k_attn<<<dim3(16, 16, 4), 512, 0, stream>>>(QKV);
  // out = Z @ Wo^T (fp32 out)
  k_gemm_bt<1><<<dim3(64, 16), 256, 0, stream>>>(QKV, QW, Wob, 2048, d_out, 2048, 2048);
}

// Round 13
// 476.327 us; speedup vs baseline: 1.6302x; 1.0566x over previous
//
#include <hip/hip_runtime.h>
#include <hip/hip_bf16.h>
#include <math.h>

typedef unsigned short u16;
typedef unsigned int u32;
typedef __attribute__((ext_vector_type(8))) short short8;
typedef __attribute__((ext_vector_type(8))) u16 ushort8;
typedef __attribute__((ext_vector_type(4))) float f32x4;
typedef __attribute__((ext_vector_type(16))) float f32x16;
typedef __attribute__((ext_vector_type(2))) u32 u32x2;

#define N_B 4
#define L_S 2048
#define E_D 2048
#define NH 16
#define HD 128
#define WIN 1024
#define QW 3072  // QKV buffer row width: 2048 q | 512 k | 512 v
#define LOG2E 1.4426950408889634f

static __device__ __forceinline__ u16 f32_bf16(float f) {
  u32 u = __builtin_bit_cast(u32, f);
  u = (u + 0x7fffu + ((u >> 16) & 1u)) >> 16;  // RNE
  return (u16)u;
}
static __device__ __forceinline__ float bf16_f32(u16 h) {
  u32 u = ((u32)h) << 16;
  return __builtin_bit_cast(float, u);
}
static __device__ __forceinline__ u32 pack_bf16_pair(float lo, float hi) {
  return (u32)f32_bf16(lo) | ((u32)f32_bf16(hi) << 16);  // low half = lo
}
static __device__ __forceinline__ void gload_lds16(const void* g, void* l) {
  __builtin_amdgcn_global_load_lds((__attribute__((address_space(1))) void*)g,
                                   (__attribute__((address_space(3))) void*)l, 16, 0, 0);
}

// ---------------- fp32 -> bf16 cast (n multiple of 8) ----------------
__global__ void k_cast(const float* __restrict__ src, u16* __restrict__ dst, int n8) {
  int i = blockIdx.x * blockDim.x + threadIdx.x;
  if (i >= n8) return;
  const float4* s = (const float4*)src + (size_t)i * 2;
  float4 a = s[0], b = s[1];
  ushort8 v;
  v[0] = f32_bf16(a.x); v[1] = f32_bf16(a.y); v[2] = f32_bf16(a.z); v[3] = f32_bf16(a.w);
  v[4] = f32_bf16(b.x); v[5] = f32_bf16(b.y); v[6] = f32_bf16(b.z); v[7] = f32_bf16(b.w);
  *((ushort8*)dst + i) = v;
}

// ---------------- RoPE cos/sin table: [L][64] ----------------
__global__ void k_rope_table(float* __restrict__ cs, float* __restrict__ sn) {
  int idx = blockIdx.x * blockDim.x + threadIdx.x;  // 2048*64
  int l = idx >> 6, f = idx & 63;
  float freq = exp2f(-(float)f * (13.287712379549449f / 64.0f));  // 10000^(-2f/128)
  float ang = (float)l * freq;
  cs[idx] = cosf(ang);
  sn[idx] = sinf(ang);
}

// ---------------- interleaved RoPE applied in place to Q and K of QKV ----------------
__global__ void k_rope_apply(u16* __restrict__ QKV, const float* __restrict__ cs,
                             const float* __restrict__ sn) {
  int idx = blockIdx.x * blockDim.x + threadIdx.x;  // 8192*20*64 exactly
  int f = idx & 63;
  int rest = idx >> 6;
  int hh = rest % 20;          // 0..15 q heads, 16..19 kv heads
  int row = rest / 20;         // 0..8191 (= n*L + l)
  int l = row & (L_S - 1);
  int col = (hh < NH) ? (hh * HD + 2 * f) : (E_D + (hh - NH) * HD + 2 * f);
  u32* p = (u32*)(QKV + (size_t)row * QW + col);
  u32 v = *p;
  float xr = bf16_f32((u16)(v & 0xffffu));
  float xi = bf16_f32((u16)(v >> 16));
  float c = cs[l * 64 + f], s = sn[l * 64 + f];
  float orr = xr * c - xi * s;
  float oii = xr * s + xi * c;
  *p = (u32)f32_bf16(orr) | ((u32)f32_bf16(oii) << 16);
}

// ---------------- C = A @ B^T, bf16 in, bf16 or f32 out ----------------
// A: MxK row-major (lda), B: NxK row-major (ldb). 128x128 tile, BK=64, 4 waves.
// XCD-aware block swizzle (T1): nwg%8==0 for both launches -> bijective.
template <int OUT_F32>
__global__ __launch_bounds__(256) void k_gemm_bt(
    const u16* __restrict__ A, int lda,
    const u16* __restrict__ B, int ldb,
    void* __restrict__ Cp, int ldc, int K) {
  __shared__ __align__(16) u16 As[128 * 64];
  __shared__ __align__(16) u16 Bs[128 * 64];
  const int tid = threadIdx.x;
  const int lane = tid & 63, w = tid >> 6;
  const int lr = lane & 15, lg = lane >> 4;
  const int gx = gridDim.x, nwg = gx * gridDim.y;
  const int fid = blockIdx.y * gx + blockIdx.x;
  const int cpx = nwg >> 3;
  const int sid = (fid & 7) * cpx + (fid >> 3);
  const int m0 = (sid % gx) * 128, n0 = (sid / gx) * 128;
  const int wm = (w >> 1) * 64, wn = (w & 1) * 64;
  const int srow = tid >> 3, scol = (tid & 7) * 8;  // staging: 16B per lane
  const f32x4 z4 = {0.f, 0.f, 0.f, 0.f};
  f32x4 acc[4][4];
#pragma unroll
  for (int i = 0; i < 4; ++i)
#pragma unroll
    for (int j = 0; j < 4; ++j) acc[i][j] = z4;
  for (int kt = 0; kt < K; kt += 64) {
#pragma unroll
    for (int rr = 0; rr < 4; ++rr) {
      gload_lds16(A + (size_t)(m0 + rr * 32 + srow) * lda + kt + scol,
                  (char*)As + rr * 4096 + w * 1024);
      gload_lds16(B + (size_t)(n0 + rr * 32 + srow) * ldb + kt + scol,
                  (char*)Bs + rr * 4096 + w * 1024);
    }
    __syncthreads();
#pragma unroll
    for (int kk = 0; kk < 64; kk += 32) {
      short8 af[4], bfr[4];
#pragma unroll
      for (int mi = 0; mi < 4; ++mi)
        af[mi] = *(const short8*)(As + (wm + mi * 16 + lr) * 64 + kk + lg * 8);
#pragma unroll
      for (int ni = 0; ni < 4; ++ni)
        bfr[ni] = *(const short8*)(Bs + (wn + ni * 16 + lr) * 64 + kk + lg * 8);
#pragma unroll
      for (int mi = 0; mi < 4; ++mi)
#pragma unroll
        for (int ni = 0; ni < 4; ++ni)
          acc[mi][ni] =
              __builtin_amdgcn_mfma_f32_16x16x32_bf16(af[mi], bfr[ni], acc[mi][ni], 0, 0, 0);
    }
    __syncthreads();
  }
#pragma unroll
  for (int mi = 0; mi < 4; ++mi)
#pragma unroll
    for (int ni = 0; ni < 4; ++ni)
#pragma unroll
      for (int j = 0; j < 4; ++j) {
        size_t r = (size_t)(m0 + wm + mi * 16 + lg * 4 + j);
        int c = n0 + wn + ni * 16 + lr;
        if (OUT_F32)
          ((float*)Cp)[r * ldc + c] = acc[mi][ni][j];
        else
          ((u16*)Cp)[r * ldc + c] = f32_bf16(acc[mi][ni][j]);
      }
}

// ---------------- sliding-window flash attention (pipelined, 8 waves, 32x32 MFMA) ----
// Grid (L/256, H, N). 8 waves; wave w owns q-rows [qb*256+w*32, +32). KV tile = 64.
// SWAPPED QK^T at 32x32: s[g] = mfma_32x32x16(K_frag, Q_frag) -> C[kv][q]:
// col=lane&31=q, row=(reg&3)+8*(reg>>2)+4*(lane>>5)=kv (guide-verified C/D layout).
// Each lane owns ONE q-row; cross-lane softmax reduce = 1 shfl_xor(32) each for
// max/sum. P packed in r-quads (kv-contiguous) -> 8 ds_write_b64. PV at 32x32:
// A=P[q][kv], B=V^T[d][kv] -> C rows=q, col=d. kf/vf LDS reads HALVE per q vs 16x16.
// K double-buffered (global_load_lds, pre-swizzled source); V single-buffered
// (reg-staged). LDS = 32K(K) + 16K(V) + 32K(P) = 80 KB, 1 block/CU.
__global__ __launch_bounds__(512, 1) void k_attn(u16* __restrict__ QKV) {
  const int qb = blockIdx.x, h = blockIdx.y, b = blockIdx.z;
  const int tid = threadIdx.x;
  const int lane = tid & 63, w = tid >> 6;      // 8 waves
  const int l31 = lane & 31, hi = lane >> 5;
  const int kh = h >> 2;
  const int qs = qb * 256 + w * 32;
  __shared__ __align__(16) u16 Klds[2][64 * 128];  // [kv][d], swizzled, 2 buffers
  __shared__ __align__(16) u16 Vt[128 * 64];       // [d][kv], swizzled, 1 buffer
  __shared__ __align__(16) u16 Plds[8][32 * 64];   // per-wave P, swizzled
  char* Pb = (char*)(&Plds[w][0]);
  char* Vb = (char*)Vt;
  const int swzq = (l31 & 7) << 4;                 // read swizzle key (row = q or d)
  const float SCL2 = 0.08838834764831845f * 1.4426950408889634f;  // scale*log2(e)
  const size_t bL = (size_t)b * L_S;
  const int q = qs + l31;
  const size_t rowQ = (bL + q) * QW + h * HD;
  // Q as B-frags: qf[ds] = Q[q][ds*16 + hi*8 .. +7]
  short8 qf[8];
#pragma unroll
  for (int ds = 0; ds < 8; ++ds)
    qf[ds] = *(const short8*)(QKV + rowQ + ds * 16 + hi * 8);
  f32x16 o[4];
#pragma unroll
  for (int dt = 0; dt < 4; ++dt)
#pragma unroll
    for (int r = 0; r < 16; ++r) o[dt][r] = 0.f;
  float m2 = -3e38f, lsum = 0.f;  // per-lane stats for this lane's q (log2 domain)
  int t0 = qb * 256 - (WIN - 1);
  if (t0 < 0) t0 = 0;
  t0 >>= 6;
  const int t1 = 4 * qb + 3;  // == (qb*256+255)>>6
  short8 vreg[2];

  // --- staging helpers (512 threads) --- identical mechanics to prior rounds
  auto ISSUE_K = [&](int t, int buf) {
    char* Kb = (char*)Klds + buf * 16384;
#pragma unroll
    for (int rr = 0; rr < 2; ++rr) {
      int row = rr * 32 + (tid >> 4);              // 0..63
      int colb = ((tid & 15) * 16) ^ ((row & 7) << 4);  // inverse-swizzled source
      gload_lds16(QKV + (bL + t * 64 + row) * QW + E_D + kh * HD + (colb >> 1),
                  Kb + rr * 8192 + w * 1024 + (lane << 4));
    }
  };
  auto LOAD_V = [&](int t) {
#pragma unroll
    for (int rr = 0; rr < 2; ++rr)
      vreg[rr] = *(const short8*)(QKV + (bL + t * 64 + lane) * QW + E_D + 512 + kh * HD +
                                  ((w * 2 + rr) * 8));
  };
  auto WRITE_V = [&]() {
#pragma unroll
    for (int rr = 0; rr < 2; ++rr) {
      int db = (w * 2 + rr) * 8;                   // multiple of 8 -> row&7 == e
#pragma unroll
      for (int e = 0; e < 8; ++e)
        *(u16*)(Vb + ((((db + e) * 128) + lane * 2) ^ (e << 4))) = (u16)vreg[rr][e];
    }
  };

  // --- prologue: stage tile t0 ---
  LOAD_V(t0);
  ISSUE_K(t0, 0);
  __syncthreads();          // drains K gloads + V reg loads
  WRITE_V();                // Vt holds tile t0; visible at barrier1 of iter t0
  int c = 0;

  for (int t = t0; t <= t1; ++t) {
    const int kv0 = t * 64;
    const int tn = (t < t1) ? t + 1 : t1;
    // prefetch next tile: K -> Klds[c^1] (async), V -> regs. Both fly until barrier1.
    ISSUE_K(tn, c ^ 1);
    LOAD_V(tn);
    // --- S^T = K Q^T from Klds[c]: two 32-kv groups, 8 d-slices each ---
    char* Kb = (char*)Klds + c * 16384;
    f32x16 s[2];
#pragma unroll
    for (int g = 0; g < 2; ++g)
#pragma unroll
      for (int r = 0; r < 16; ++r) s[g][r] = 0.f;
#pragma unroll
    for (int g = 0; g < 2; ++g) {
      const int r = g * 32 + l31;                  // K row this lane reads
      const int rsw = (r & 7) << 4;
#pragma unroll
      for (int ds = 0; ds < 8; ++ds) {
        short8 kf = *(const short8*)(Kb + (r * 256 + ((ds * 32 + hi * 16) ^ rsw)));
        s[g] = __builtin_amdgcn_mfma_f32_32x32x16_bf16(kf, qf[ds], s[g], 0, 0, 0);
      }
    }
    // --- lane-local masked scores (log2 domain); kv = kv0+g*32+(r&3)+8*(r>>2)+4*hi ---
    float v[2][16];
    float mx = -3e38f;
#pragma unroll
    for (int g = 0; g < 2; ++g)
#pragma unroll
      for (int r = 0; r < 16; ++r) {
        int kg = kv0 + g * 32 + (r & 3) + 8 * (r >> 2) + 4 * hi;
        bool a = (kg <= q) && (kg > q - WIN);
        float vv = a ? s[g][r] * SCL2 : -3e38f;
        v[g][r] = vv;
        mx = fmaxf(mx, vv);
      }
    mx = fmaxf(mx, __shfl_xor(mx, 32));            // partner lane has other kv half
    // defer-max (T13): 8 nats = 11.5416 bits; wave-uniform branch
    if (__ballot(mx > m2 + 11.5415603f)) {
      float mn = fmaxf(m2, mx);
      float alpha = exp2f(m2 - mn);
      m2 = mn;
      lsum *= alpha;
#pragma unroll
      for (int r = 0; r < 16; ++r) {
        float alr = __shfl(alpha, (r & 3) + 8 * (r >> 2) + 4 * hi);
#pragma unroll
        for (int dt = 0; dt < 4; ++dt) o[dt][r] *= alr;
      }
    }
    // exp + sum
    float rs = 0.f;
#pragma unroll
    for (int g = 0; g < 2; ++g)
#pragma unroll
      for (int r = 0; r < 16; ++r) {
        float pe = (v[g][r] > -1e37f) ? exp2f(v[g][r] - m2) : 0.f;
        v[g][r] = pe;
        rs += pe;
      }
    rs += __shfl_xor(rs, 32);
    lsum += rs;
    // P -> wave-private LDS: r-quads are kv-contiguous -> 8x ds_write_b64
#pragma unroll
    for (int g = 0; g < 2; ++g)
#pragma unroll
      for (int cq = 0; cq < 4; ++cq) {
        u32x2 d2;
        d2[0] = pack_bf16_pair(v[g][cq * 4 + 0], v[g][cq * 4 + 1]);
        d2[1] = pack_bf16_pair(v[g][cq * 4 + 2], v[g][cq * 4 + 3]);
        int baseb = (g * 32 + 8 * cq + 4 * hi) * 2;       // byte col, 8-aligned
        *(u32x2*)(Pb + (l31 * 128 + (baseb ^ swzq))) = d2;
      }
    __syncthreads();  // barrier1: drains K(tn)+V(tn) loads; P + Vt(current) visible
    // --- O += P V from Vt ---
    short8 pf[4];
#pragma unroll
    for (int ks = 0; ks < 4; ++ks)
      pf[ks] = *(const short8*)(Pb + (l31 * 128 + ((ks * 32 + hi * 16) ^ swzq)));
    __builtin_amdgcn_s_setprio(1);
#pragma unroll
    for (int dt = 0; dt < 4; ++dt) {
      const int d = dt * 32 + l31;
      const int dsw = (d & 7) << 4;                // == swzq
#pragma unroll
      for (int ks = 0; ks < 4; ++ks) {
        short8 vf = *(const short8*)(Vb + (d * 128 + ((ks * 32 + hi * 16) ^ dsw)));
        o[dt] = __builtin_amdgcn_mfma_f32_32x32x16_bf16(pf[ks], vf, o[dt], 0, 0, 0);
      }
    }
    __builtin_amdgcn_s_setprio(0);
    __syncthreads();  // barrier2: all PV reads of Vt done -> safe to overwrite
    WRITE_V();        // stage V(tn); visible to PV(t+1) via barrier1(t+1)
    c ^= 1;
  }
  // epilogue: normalize and write. o rows are q' = qs+(r&3)+8*(r>>2)+4*hi, col = dt*32+l31
  float inv = 1.0f / lsum;
#pragma unroll
  for (int r = 0; r < 16; ++r) {
    int ridx = (r & 3) + 8 * (r >> 2) + 4 * hi;
    float invr = __shfl(inv, ridx);
    size_t rowO = (bL + qs + ridx) * QW + h * HD + l31;
#pragma unroll
    for (int dt = 0; dt < 4; ++dt)
      QKV[rowO + dt * 32] = f32_bf16(o[dt][r] * invr);
  }
}

extern "C" void kernel_launch(void* const* d_in, const int* in_sizes, int n_in,
                              void* d_out, int out_size, void* d_ws, size_t ws_size,
                              hipStream_t stream) {
  const float* x  = (const float*)d_in[0];
  const float* Wq = (const float*)d_in[1];
  const float* Wk = (const float*)d_in[2];
  const float* Wv = (const float*)d_in[3];
  const float* Wo = (const float*)d_in[4];
  char* ws = (char*)d_ws;
  // Workspace layout (total 105,906,176 B). If the harness workspace is too
  // small, bail out cleanly (validation fails loudly instead of GPU faulting).
  if (ws_size < 105906176u) return;
  u16* xb    = (u16*)(ws);                    // 8192*2048*2 = 33554432
  u16* Wqkv  = (u16*)(ws + 33554432);         // 3072*2048*2 = 12582912
  u16* Wob   = (u16*)(ws + 46137344);         // 2048*2048*2 =  8388608
  u16* QKV   = (u16*)(ws + 54525952);         // 8192*3072*2 = 50331648
  float* cs  = (float*)(ws + 104857600);      // 131072*4    =   524288
  float* sn  = (float*)(ws + 105381888);      // total end 105906176 B

  // bf16 casts (weights packed: Wq rows 0..2047 | Wk rows 2048..2559 | Wv rows 2560..3071)
  k_cast<<<8192, 256, 0, stream>>>(x, xb, 16777216 / 8);
  k_cast<<<2048, 256, 0, stream>>>(Wq, Wqkv, 4194304 / 8);
  k_cast<<<512, 256, 0, stream>>>(Wk, Wqkv + 2048 * 2048, 1048576 / 8);
  k_cast<<<512, 256, 0, stream>>>(Wv, Wqkv + 2560 * 2048, 1048576 / 8);
  k_cast<<<2048, 256, 0, stream>>>(Wo, Wob, 4194304 / 8);
  k_rope_table<<<512, 256, 0, stream>>>(cs, sn);
  // fused QKV projection: [Q|K|V] = xb @ Wqkv^T
  k_gemm_bt<0><<<dim3(64, 24), 256, 0, stream>>>(xb, 2048, Wqkv, 2048, QKV, QW, 2048);
  // RoPE in place on Q and K regions
  k_rope_apply<<<40960, 256, 0, stream>>>(QKV, cs, sn);
  // flash attention; Z overwrites Q region of QKV
  k_attn<<<dim3(8, 16, 4), 512, 0, stream>>>(QKV);
  // out = Z @ Wo^T (fp32 out)
  k_gemm_bt<1><<<dim3(64, 16), 256, 0, stream>>>(QKV, QW, Wob, 2048, d_out, 2048, 2048);
}

// Round 14
// 463.896 us; speedup vs baseline: 1.6739x; 1.0268x over previous
//
#include <hip/hip_runtime.h>
#include <hip/hip_bf16.h>
#include <math.h>

typedef unsigned short u16;
typedef unsigned int u32;
typedef __attribute__((ext_vector_type(8))) short short8;
typedef __attribute__((ext_vector_type(8))) u16 ushort8;
typedef __attribute__((ext_vector_type(4))) float f32x4;
typedef __attribute__((ext_vector_type(16))) float f32x16;
typedef __attribute__((ext_vector_type(4))) u32 u32x4;

#define N_B 4
#define L_S 2048
#define E_D 2048
#define NH 16
#define HD 128
#define WIN 1024
#define QW 3072  // QKV buffer row width: 2048 q | 512 k | 512 v
#define LOG2E 1.4426950408889634f

static __device__ __forceinline__ u16 f32_bf16(float f) {
  u32 u = __builtin_bit_cast(u32, f);
  u = (u + 0x7fffu + ((u >> 16) & 1u)) >> 16;  // RNE
  return (u16)u;
}
static __device__ __forceinline__ float bf16_f32(u16 h) {
  u32 u = ((u32)h) << 16;
  return __builtin_bit_cast(float, u);
}
static __device__ __forceinline__ u32 pack_bf16_pair(float lo, float hi) {
  return (u32)f32_bf16(lo) | ((u32)f32_bf16(hi) << 16);  // low half = lo
}
static __device__ __forceinline__ void gload_lds16(const void* g, void* l) {
  __builtin_amdgcn_global_load_lds((__attribute__((address_space(1))) void*)g,
                                   (__attribute__((address_space(3))) void*)l, 16, 0, 0);
}

// ---------------- fp32 -> bf16 cast (n multiple of 8) ----------------
__global__ void k_cast(const float* __restrict__ src, u16* __restrict__ dst, int n8) {
  int i = blockIdx.x * blockDim.x + threadIdx.x;
  if (i >= n8) return;
  const float4* s = (const float4*)src + (size_t)i * 2;
  float4 a = s[0], b = s[1];
  ushort8 v;
  v[0] = f32_bf16(a.x); v[1] = f32_bf16(a.y); v[2] = f32_bf16(a.z); v[3] = f32_bf16(a.w);
  v[4] = f32_bf16(b.x); v[5] = f32_bf16(b.y); v[6] = f32_bf16(b.z); v[7] = f32_bf16(b.w);
  *((ushort8*)dst + i) = v;
}

// ---------------- RoPE cos/sin table: [L][64] ----------------
__global__ void k_rope_table(float* __restrict__ cs, float* __restrict__ sn) {
  int idx = blockIdx.x * blockDim.x + threadIdx.x;  // 2048*64
  int l = idx >> 6, f = idx & 63;
  float freq = exp2f(-(float)f * (13.287712379549449f / 64.0f));  // 10000^(-2f/128)
  float ang = (float)l * freq;
  cs[idx] = cosf(ang);
  sn[idx] = sinf(ang);
}

// ---------------- interleaved RoPE applied in place to Q and K of QKV ----------------
__global__ void k_rope_apply(u16* __restrict__ QKV, const float* __restrict__ cs,
                             const float* __restrict__ sn) {
  int idx = blockIdx.x * blockDim.x + threadIdx.x;  // 8192*20*64 exactly
  int f = idx & 63;
  int rest = idx >> 6;
  int hh = rest % 20;          // 0..15 q heads, 16..19 kv heads
  int row = rest / 20;         // 0..8191 (= n*L + l)
  int l = row & (L_S - 1);
  int col = (hh < NH) ? (hh * HD + 2 * f) : (E_D + (hh - NH) * HD + 2 * f);
  u32* p = (u32*)(QKV + (size_t)row * QW + col);
  u32 v = *p;
  float xr = bf16_f32((u16)(v & 0xffffu));
  float xi = bf16_f32((u16)(v >> 16));
  float c = cs[l * 64 + f], s = sn[l * 64 + f];
  float orr = xr * c - xi * s;
  float oii = xr * s + xi * c;
  *p = (u32)f32_bf16(orr) | ((u32)f32_bf16(oii) << 16);
}

// ---------------- C = A @ B^T, bf16 in, bf16 or f32 out ----------------
// A: MxK row-major (lda), B: NxK row-major (ldb). 128x128 tile, BK=64, 4 waves.
// XCD-aware block swizzle (T1): nwg%8==0 for both launches -> bijective.
template <int OUT_F32>
__global__ __launch_bounds__(256) void k_gemm_bt(
    const u16* __restrict__ A, int lda,
    const u16* __restrict__ B, int ldb,
    void* __restrict__ Cp, int ldc, int K) {
  __shared__ __align__(16) u16 As[128 * 64];
  __shared__ __align__(16) u16 Bs[128 * 64];
  const int tid = threadIdx.x;
  const int lane = tid & 63, w = tid >> 6;
  const int lr = lane & 15, lg = lane >> 4;
  const int gx = gridDim.x, nwg = gx * gridDim.y;
  const int fid = blockIdx.y * gx + blockIdx.x;
  const int cpx = nwg >> 3;
  const int sid = (fid & 7) * cpx + (fid >> 3);
  const int m0 = (sid % gx) * 128, n0 = (sid / gx) * 128;
  const int wm = (w >> 1) * 64, wn = (w & 1) * 64;
  const int srow = tid >> 3, scol = (tid & 7) * 8;  // staging: 16B per lane
  const f32x4 z4 = {0.f, 0.f, 0.f, 0.f};
  f32x4 acc[4][4];
#pragma unroll
  for (int i = 0; i < 4; ++i)
#pragma unroll
    for (int j = 0; j < 4; ++j) acc[i][j] = z4;
  for (int kt = 0; kt < K; kt += 64) {
#pragma unroll
    for (int rr = 0; rr < 4; ++rr) {
      gload_lds16(A + (size_t)(m0 + rr * 32 + srow) * lda + kt + scol,
                  (char*)As + rr * 4096 + w * 1024);
      gload_lds16(B + (size_t)(n0 + rr * 32 + srow) * ldb + kt + scol,
                  (char*)Bs + rr * 4096 + w * 1024);
    }
    __syncthreads();
#pragma unroll
    for (int kk = 0; kk < 64; kk += 32) {
      short8 af[4], bfr[4];
#pragma unroll
      for (int mi = 0; mi < 4; ++mi)
        af[mi] = *(const short8*)(As + (wm + mi * 16 + lr) * 64 + kk + lg * 8);
#pragma unroll
      for (int ni = 0; ni < 4; ++ni)
        bfr[ni] = *(const short8*)(Bs + (wn + ni * 16 + lr) * 64 + kk + lg * 8);
#pragma unroll
      for (int mi = 0; mi < 4; ++mi)
#pragma unroll
        for (int ni = 0; ni < 4; ++ni)
          acc[mi][ni] =
              __builtin_amdgcn_mfma_f32_16x16x32_bf16(af[mi], bfr[ni], acc[mi][ni], 0, 0, 0);
    }
    __syncthreads();
  }
#pragma unroll
  for (int mi = 0; mi < 4; ++mi)
#pragma unroll
    for (int ni = 0; ni < 4; ++ni)
#pragma unroll
      for (int j = 0; j < 4; ++j) {
        size_t r = (size_t)(m0 + wm + mi * 16 + lg * 4 + j);
        int c = n0 + wn + ni * 16 + lr;
        if (OUT_F32)
          ((float*)Cp)[r * ldc + c] = acc[mi][ni][j];
        else
          ((u16*)Cp)[r * ldc + c] = f32_bf16(acc[mi][ni][j]);
      }
}

// ---------------- sliding-window flash attention (pipelined, 8 waves, 32x32 MFMA) ----
// Grid (L/256, H, N). 8 waves; wave w owns q-rows [qb*256+w*32, +32). KV tile = 64.
// SWAPPED QK^T at 32x32 -> C[kv][q]: col=lane&31=q, row=(reg&3)+8*(reg>>2)+4*hi=kv.
// P is kept ENTIRELY IN REGISTERS: packed to bf16-pair words; the partner lane's
// kv-half is fetched with 4 __shfl_xor(.,32) per 32-kv group; PV A-frags are
// assembled from 4 u32 words (own quad + partner quad, kv-ascending; derivation
// verified for both hi halves). No P LDS -> LDS = 32K(Kdbuf) + 16K(V) = 48 KB ->
// 2 blocks/CU under __launch_bounds__(512,2) (VGPR cap 128, r7/r8 semantics):
// all 512 blocks co-resident, tail imbalance absorbed.
// Per-wave tile skip: wave skips compute on tiles fully outside its 32-row window
// (staging + barriers remain block-wide; all skip predicates wave-uniform).
__global__ __launch_bounds__(512, 2) void k_attn(u16* __restrict__ QKV) {
  const int qb = blockIdx.x, h = blockIdx.y, b = blockIdx.z;
  const int tid = threadIdx.x;
  const int lane = tid & 63, w = tid >> 6;      // 8 waves
  const int l31 = lane & 31, hi = lane >> 5;
  const int kh = h >> 2;
  const int qs = qb * 256 + w * 32;
  __shared__ __align__(16) u16 Klds[2][64 * 128];  // [kv][d], swizzled, 2 buffers
  __shared__ __align__(16) u16 Vt[128 * 64];       // [d][kv], swizzled, 1 buffer
  char* Vb = (char*)Vt;
  const float SCL2 = 0.08838834764831845f * 1.4426950408889634f;  // scale*log2(e)
  const size_t bL = (size_t)b * L_S;
  const int q = qs + l31;
  const size_t rowQ = (bL + q) * QW + h * HD;
  // Q as B-frags: qf[ds] = Q[q][ds*16 + hi*8 .. +7]
  short8 qf[8];
#pragma unroll
  for (int ds = 0; ds < 8; ++ds)
    qf[ds] = *(const short8*)(QKV + rowQ + ds * 16 + hi * 8);
  f32x16 o[4];
#pragma unroll
  for (int dt = 0; dt < 4; ++dt)
#pragma unroll
    for (int r = 0; r < 16; ++r) o[dt][r] = 0.f;
  float m2 = -3e38f, lsum = 0.f;  // per-lane stats for this lane's q (log2 domain)
  int t0 = qb * 256 - (WIN - 1);
  if (t0 < 0) t0 = 0;
  t0 >>= 6;
  const int t1 = 4 * qb + 3;  // == (qb*256+255)>>6
  short8 vreg[2];

  // --- staging helpers (512 threads) ---
  auto ISSUE_K = [&](int t, int buf) {
    char* Kb = (char*)Klds + buf * 16384;
#pragma unroll
    for (int rr = 0; rr < 2; ++rr) {
      int row = rr * 32 + (tid >> 4);              // 0..63
      int colb = ((tid & 15) * 16) ^ ((row & 7) << 4);  // inverse-swizzled source
      gload_lds16(QKV + (bL + t * 64 + row) * QW + E_D + kh * HD + (colb >> 1),
                  Kb + rr * 8192 + w * 1024 + (lane << 4));
    }
  };
  auto LOAD_V = [&](int t) {
#pragma unroll
    for (int rr = 0; rr < 2; ++rr)
      vreg[rr] = *(const short8*)(QKV + (bL + t * 64 + lane) * QW + E_D + 512 + kh * HD +
                                  ((w * 2 + rr) * 8));
  };
  auto WRITE_V = [&]() {
#pragma unroll
    for (int rr = 0; rr < 2; ++rr) {
      int db = (w * 2 + rr) * 8;                   // multiple of 8 -> row&7 == e
#pragma unroll
      for (int e = 0; e < 8; ++e)
        *(u16*)(Vb + ((((db + e) * 128) + lane * 2) ^ (e << 4))) = (u16)vreg[rr][e];
    }
  };

  // --- prologue: stage tile t0 ---
  LOAD_V(t0);
  ISSUE_K(t0, 0);
  __syncthreads();          // drains K gloads + V reg loads
  WRITE_V();                // Vt holds tile t0; visible at barrier1 of iter t0
  int c = 0;

  for (int t = t0; t <= t1; ++t) {
    const int kv0 = t * 64;
    const int tn = (t < t1) ? t + 1 : t1;
    // prefetch next tile: K -> Klds[c^1] (async), V -> regs. Both fly until barrier1.
    ISSUE_K(tn, c ^ 1);
    LOAD_V(tn);
    // per-wave activity: does [kv0, kv0+63] intersect this wave's allowed range?
    const bool act = (kv0 <= qs + 31) && (kv0 + 63 > qs - WIN);
    u32x4 pa[4];  // assembled PV A-frags (bf16 x8 each)
    if (act) {
      // --- S^T = K Q^T from Klds[c]: two 32-kv groups, 8 d-slices each ---
      char* Kb = (char*)Klds + c * 16384;
      f32x16 s[2];
#pragma unroll
      for (int g = 0; g < 2; ++g)
#pragma unroll
        for (int r = 0; r < 16; ++r) s[g][r] = 0.f;
#pragma unroll
      for (int g = 0; g < 2; ++g) {
        const int r = g * 32 + l31;                  // K row this lane reads
        const int rsw = (r & 7) << 4;
#pragma unroll
        for (int ds = 0; ds < 8; ++ds) {
          short8 kf = *(const short8*)(Kb + (r * 256 + ((ds * 32 + hi * 16) ^ rsw)));
          s[g] = __builtin_amdgcn_mfma_f32_32x32x16_bf16(kf, qf[ds], s[g], 0, 0, 0);
        }
      }
      // --- masked scores (log2 domain); kv = kv0+g*32+(r&3)+8*(r>>2)+4*hi ---
      float v[2][16];
      float mx = -3e38f;
#pragma unroll
      for (int g = 0; g < 2; ++g)
#pragma unroll
        for (int r = 0; r < 16; ++r) {
          int kg = kv0 + g * 32 + (r & 3) + 8 * (r >> 2) + 4 * hi;
          bool a = (kg <= q) && (kg > q - WIN);
          float vv = a ? s[g][r] * SCL2 : -3e38f;
          v[g][r] = vv;
          mx = fmaxf(mx, vv);
        }
      mx = fmaxf(mx, __shfl_xor(mx, 32));            // partner has other kv half
      // defer-max (T13): 8 nats = 11.5416 bits; wave-uniform branch
      if (__ballot(mx > m2 + 11.5415603f)) {
        float mn = fmaxf(m2, mx);
        float alpha = exp2f(m2 - mn);
        m2 = mn;
        lsum *= alpha;
#pragma unroll
        for (int r = 0; r < 16; ++r) {
          float alr = __shfl(alpha, (r & 3) + 8 * (r >> 2) + 4 * hi);
#pragma unroll
          for (int dt = 0; dt < 4; ++dt) o[dt][r] *= alr;
        }
      }
      // exp + sum
      float rs = 0.f;
#pragma unroll
      for (int g = 0; g < 2; ++g)
#pragma unroll
        for (int r = 0; r < 16; ++r) {
          float pe = (v[g][r] > -1e37f) ? exp2f(v[g][r] - m2) : 0.f;
          v[g][r] = pe;
          rs += pe;
        }
      rs += __shfl_xor(rs, 32);
      lsum += rs;
      // --- P stays in registers: pack words + partner exchange ---
      // W[g][2qi+u] covers kv = g*32 + 8*qi + 4*hi + {2u, 2u+1}
#pragma unroll
      for (int g = 0; g < 2; ++g) {
        u32 W[8];
#pragma unroll
        for (int qi = 0; qi < 4; ++qi) {
          W[2 * qi]     = pack_bf16_pair(v[g][4 * qi + 0], v[g][4 * qi + 1]);
          W[2 * qi + 1] = pack_bf16_pair(v[g][4 * qi + 2], v[g][4 * qi + 3]);
        }
        // supply what partner needs; receive what we need (symmetric xor-32)
        u32 R[4];
        R[0] = __shfl_xor(hi ? W[0] : W[2], 32);
        R[1] = __shfl_xor(hi ? W[1] : W[3], 32);
        R[2] = __shfl_xor(hi ? W[4] : W[6], 32);
        R[3] = __shfl_xor(hi ? W[5] : W[7], 32);
        // frag(ksl): kv = (g*2+ksl)*16 + hi*8 + 0..7, kv-ascending
#pragma unroll
        for (int ksl = 0; ksl < 2; ++ksl) {
          u32x4 fr;
          if (hi == 0) {
            fr[0] = W[4 * ksl]; fr[1] = W[4 * ksl + 1];
            fr[2] = R[2 * ksl]; fr[3] = R[2 * ksl + 1];
          } else {
            fr[0] = R[2 * ksl]; fr[1] = R[2 * ksl + 1];
            fr[2] = W[4 * ksl + 2]; fr[3] = W[4 * ksl + 3];
          }
          pa[g * 2 + ksl] = fr;
        }
      }
    }
    __syncthreads();  // barrier1: drains K(tn)+V(tn) loads; Vt(current) visible
    if (act) {
      // --- O += P V from Vt ---
      __builtin_amdgcn_s_setprio(1);
#pragma unroll
      for (int dt = 0; dt < 4; ++dt) {
        const int d = dt * 32 + l31;
        const int dsw = (d & 7) << 4;
#pragma unroll
        for (int ks = 0; ks < 4; ++ks) {
          short8 vf = *(const short8*)(Vb + (d * 128 + ((ks * 32 + hi * 16) ^ dsw)));
          o[dt] = __builtin_amdgcn_mfma_f32_32x32x16_bf16(
              __builtin_bit_cast(short8, pa[ks]), vf, o[dt], 0, 0, 0);
        }
      }
      __builtin_amdgcn_s_setprio(0);
    }
    __syncthreads();  // barrier2: all PV reads of Vt done -> safe to overwrite
    WRITE_V();        // stage V(tn); visible to PV(t+1) via barrier1(t+1)
    c ^= 1;
  }
  // epilogue: normalize and write. o rows are q' = qs+(r&3)+8*(r>>2)+4*hi, col = dt*32+l31
  float inv = 1.0f / lsum;
#pragma unroll
  for (int r = 0; r < 16; ++r) {
    int ridx = (r & 3) + 8 * (r >> 2) + 4 * hi;
    float invr = __shfl(inv, ridx);
    size_t rowO = (bL + qs + ridx) * QW + h * HD + l31;
#pragma unroll
    for (int dt = 0; dt < 4; ++dt)
      QKV[rowO + dt * 32] = f32_bf16(o[dt][r] * invr);
  }
}

extern "C" void kernel_launch(void* const* d_in, const int* in_sizes, int n_in,
                              void* d_out, int out_size, void* d_ws, size_t ws_size,
                              hipStream_t stream) {
  const float* x  = (const float*)d_in[0];
  const float* Wq = (const float*)d_in[1];
  const float* Wk = (const float*)d_in[2];
  const float* Wv = (const float*)d_in[3];
  const float* Wo = (const float*)d_in[4];
  char* ws = (char*)d_ws;
  // Workspace layout (total 105,906,176 B). If the harness workspace is too
  // small, bail out cleanly (validation fails loudly instead of GPU faulting).
  if (ws_size < 105906176u) return;
  u16* xb    = (u16*)(ws);                    // 8192*2048*2 = 33554432
  u16* Wqkv  = (u16*)(ws + 33554432);         // 3072*2048*2 = 12582912
  u16* Wob   = (u16*)(ws + 46137344);         // 2048*2048*2 =  8388608
  u16* QKV   = (u16*)(ws + 54525952);         // 8192*3072*2 = 50331648
  float* cs  = (float*)(ws + 104857600);      // 131072*4    =   524288
  float* sn  = (float*)(ws + 105381888);      // total end 105906176 B

  // bf16 casts (weights packed: Wq rows 0..2047 | Wk rows 2048..2559 | Wv rows 2560..3071)
  k_cast<<<8192, 256, 0, stream>>>(x, xb, 16777216 / 8);
  k_cast<<<2048, 256, 0, stream>>>(Wq, Wqkv, 4194304 / 8);
  k_cast<<<512, 256, 0, stream>>>(Wk, Wqkv + 2048 * 2048, 1048576 / 8);
  k_cast<<<512, 256, 0, stream>>>(Wv, Wqkv + 2560 * 2048, 1048576 / 8);
  k_cast<<<2048, 256, 0, stream>>>(Wo, Wob, 4194304 / 8);
  k_rope_table<<<512, 256, 0, stream>>>(cs, sn);
  // fused QKV projection: [Q|K|V] = xb @ Wqkv^T
  k_gemm_bt<0><<<dim3(64, 24), 256, 0, stream>>>(xb, 2048, Wqkv, 2048, QKV, QW, 2048);
  // RoPE in place on Q and K regions
  k_rope_apply<<<40960, 256, 0, stream>>>(QKV, cs, sn);
  // flash attention; Z overwrites Q region of QKV
  k_attn<<<dim3(8, 16, 4), 512, 0, stream>>>(QKV);
  // out = Z @ Wo^T (fp32 out)
  k_gemm_bt<1><<<dim3(64, 16), 256, 0, stream>>>(QKV, QW, Wob, 2048, d_out, 2048, 2048);
}

// Round 15
// 437.007 us; speedup vs baseline: 1.7769x; 1.0615x over previous
//
#include <hip/hip_runtime.h>
#include <hip/hip_bf16.h>
#include <math.h>

typedef unsigned short u16;
typedef unsigned int u32;
typedef __attribute__((ext_vector_type(8))) short short8;
typedef __attribute__((ext_vector_type(8))) u16 ushort8;
typedef __attribute__((ext_vector_type(4))) float f32x4;
typedef __attribute__((ext_vector_type(16))) float f32x16;
typedef __attribute__((ext_vector_type(4))) u32 u32x4;

#define N_B 4
#define L_S 2048
#define E_D 2048
#define NH 16
#define HD 128
#define WIN 1024
#define QW 3072  // QKV buffer row width: 2048 q | 512 k | 512 v
#define LOG2E 1.4426950408889634f

static __device__ __forceinline__ u16 f32_bf16(float f) {
  u32 u = __builtin_bit_cast(u32, f);
  u = (u + 0x7fffu + ((u >> 16) & 1u)) >> 16;  // RNE
  return (u16)u;
}
static __device__ __forceinline__ float bf16_f32(u16 h) {
  u32 u = ((u32)h) << 16;
  return __builtin_bit_cast(float, u);
}
static __device__ __forceinline__ u32 pack_bf16_pair(float lo, float hi) {
  __hip_bfloat162 h2 = __float22bfloat162_rn(make_float2(lo, hi));  // RNE, .x = low
  u32 r;
  __builtin_memcpy(&r, &h2, 4);
  return r;
}
static __device__ __forceinline__ void gload_lds16(const void* g, void* l) {
  __builtin_amdgcn_global_load_lds((__attribute__((address_space(1))) void*)g,
                                   (__attribute__((address_space(3))) void*)l, 16, 0, 0);
}

// ---------------- fp32 -> bf16 cast (n multiple of 8) ----------------
__global__ void k_cast(const float* __restrict__ src, u16* __restrict__ dst, int n8) {
  int i = blockIdx.x * blockDim.x + threadIdx.x;
  if (i >= n8) return;
  const float4* s = (const float4*)src + (size_t)i * 2;
  float4 a = s[0], b = s[1];
  ushort8 v;
  v[0] = f32_bf16(a.x); v[1] = f32_bf16(a.y); v[2] = f32_bf16(a.z); v[3] = f32_bf16(a.w);
  v[4] = f32_bf16(b.x); v[5] = f32_bf16(b.y); v[6] = f32_bf16(b.z); v[7] = f32_bf16(b.w);
  *((ushort8*)dst + i) = v;
}

// ---------------- RoPE cos/sin table: [L][64] ----------------
__global__ void k_rope_table(float* __restrict__ cs, float* __restrict__ sn) {
  int idx = blockIdx.x * blockDim.x + threadIdx.x;  // 2048*64
  int l = idx >> 6, f = idx & 63;
  float freq = exp2f(-(float)f * (13.287712379549449f / 64.0f));  // 10000^(-2f/128)
  float ang = (float)l * freq;
  cs[idx] = cosf(ang);
  sn[idx] = sinf(ang);
}

// ---------------- interleaved RoPE applied in place to Q and K of QKV ----------------
__global__ void k_rope_apply(u16* __restrict__ QKV, const float* __restrict__ cs,
                             const float* __restrict__ sn) {
  int idx = blockIdx.x * blockDim.x + threadIdx.x;  // 8192*20*64 exactly
  int f = idx & 63;
  int rest = idx >> 6;
  int hh = rest % 20;          // 0..15 q heads, 16..19 kv heads
  int row = rest / 20;         // 0..8191 (= n*L + l)
  int l = row & (L_S - 1);
  int col = (hh < NH) ? (hh * HD + 2 * f) : (E_D + (hh - NH) * HD + 2 * f);
  u32* p = (u32*)(QKV + (size_t)row * QW + col);
  u32 v = *p;
  float xr = bf16_f32((u16)(v & 0xffffu));
  float xi = bf16_f32((u16)(v >> 16));
  float c = cs[l * 64 + f], s = sn[l * 64 + f];
  float orr = xr * c - xi * s;
  float oii = xr * s + xi * c;
  *p = (u32)f32_bf16(orr) | ((u32)f32_bf16(oii) << 16);
}

// ---------------- C = A @ B^T, bf16 in, bf16 or f32 out ----------------
// A: MxK row-major (lda), B: NxK row-major (ldb). 128x128 tile, BK=64, 4 waves.
// XCD-aware block swizzle (T1): nwg%8==0 for both launches -> bijective.
template <int OUT_F32>
__global__ __launch_bounds__(256) void k_gemm_bt(
    const u16* __restrict__ A, int lda,
    const u16* __restrict__ B, int ldb,
    void* __restrict__ Cp, int ldc, int K) {
  __shared__ __align__(16) u16 As[128 * 64];
  __shared__ __align__(16) u16 Bs[128 * 64];
  const int tid = threadIdx.x;
  const int lane = tid & 63, w = tid >> 6;
  const int lr = lane & 15, lg = lane >> 4;
  const int gx = gridDim.x, nwg = gx * gridDim.y;
  const int fid = blockIdx.y * gx + blockIdx.x;
  const int cpx = nwg >> 3;
  const int sid = (fid & 7) * cpx + (fid >> 3);
  const int m0 = (sid % gx) * 128, n0 = (sid / gx) * 128;
  const int wm = (w >> 1) * 64, wn = (w & 1) * 64;
  const int srow = tid >> 3, scol = (tid & 7) * 8;  // staging: 16B per lane
  const f32x4 z4 = {0.f, 0.f, 0.f, 0.f};
  f32x4 acc[4][4];
#pragma unroll
  for (int i = 0; i < 4; ++i)
#pragma unroll
    for (int j = 0; j < 4; ++j) acc[i][j] = z4;
  for (int kt = 0; kt < K; kt += 64) {
#pragma unroll
    for (int rr = 0; rr < 4; ++rr) {
      gload_lds16(A + (size_t)(m0 + rr * 32 + srow) * lda + kt + scol,
                  (char*)As + rr * 4096 + w * 1024);
      gload_lds16(B + (size_t)(n0 + rr * 32 + srow) * ldb + kt + scol,
                  (char*)Bs + rr * 4096 + w * 1024);
    }
    __syncthreads();
#pragma unroll
    for (int kk = 0; kk < 64; kk += 32) {
      short8 af[4], bfr[4];
#pragma unroll
      for (int mi = 0; mi < 4; ++mi)
        af[mi] = *(const short8*)(As + (wm + mi * 16 + lr) * 64 + kk + lg * 8);
#pragma unroll
      for (int ni = 0; ni < 4; ++ni)
        bfr[ni] = *(const short8*)(Bs + (wn + ni * 16 + lr) * 64 + kk + lg * 8);
#pragma unroll
      for (int mi = 0; mi < 4; ++mi)
#pragma unroll
        for (int ni = 0; ni < 4; ++ni)
          acc[mi][ni] =
              __builtin_amdgcn_mfma_f32_16x16x32_bf16(af[mi], bfr[ni], acc[mi][ni], 0, 0, 0);
    }
    __syncthreads();
  }
#pragma unroll
  for (int mi = 0; mi < 4; ++mi)
#pragma unroll
    for (int ni = 0; ni < 4; ++ni)
#pragma unroll
      for (int j = 0; j < 4; ++j) {
        size_t r = (size_t)(m0 + wm + mi * 16 + lg * 4 + j);
        int c = n0 + wn + ni * 16 + lr;
        if (OUT_F32)
          ((float*)Cp)[r * ldc + c] = acc[mi][ni][j];
        else
          ((u16*)Cp)[r * ldc + c] = f32_bf16(acc[mi][ni][j]);
      }
}

// ---------------- sliding-window flash attention (pipelined, 8 waves, 32x32 MFMA) ----
// Grid (L/256, H, N). 8 waves; wave w owns q-rows [qb*256+w*32, +32). KV tile = 64.
// LOAD-BALANCED qb remap: qb = (b>=2) ? 7-bx : bx (bijective per (bx,b)). Blocks i
// and i+256 share a CU under either round-robin dispatch scheme and differ in b by
// 2 -> co-resident blocks get COMPLEMENTARY tile counts (pair sums 24..36 vs 40).
// SWAPPED QK^T at 32x32 -> C[kv][q]; P entirely in registers (partner-lane
// shfl_xor(32) exchange). K AND V double-buffered -> ONE barrier per tile:
// barrier1(t) drains prefetched K(t+1)/V(t+1) loads, publishes Vt[c^1] writes
// (done after barrier1(t-1)), and separates all Klds/Vt reuse (audited: QK^T(t)
// reads K[c] finish before barrier1(t), gloads into K[c] issue at t+1 after it;
// PV(t) reads Vt[c] finish before barrier1(t+1), WRITE_V into Vt[c] at t+1 after).
// LDS = 32K(K) + 32K(V) = 64 KB -> 2 blocks/CU under __launch_bounds__(512,2).
__global__ __launch_bounds__(512, 2) void k_attn(u16* __restrict__ QKV) {
  const int bx = blockIdx.x, h = blockIdx.y, b = blockIdx.z;
  const int qb = (b >= 2) ? 7 - bx : bx;        // cost-balanced remap
  const int tid = threadIdx.x;
  const int lane = tid & 63, w = tid >> 6;      // 8 waves
  const int l31 = lane & 31, hi = lane >> 5;
  const int kh = h >> 2;
  const int qs = qb * 256 + w * 32;
  __shared__ __align__(16) u16 Klds[2][64 * 128];  // [kv][d], swizzled, 2 buffers
  __shared__ __align__(16) u16 Vt[2][128 * 64];    // [d][kv], swizzled, 2 buffers
  const float SCL2 = 0.08838834764831845f * 1.4426950408889634f;  // scale*log2(e)
  const size_t bL = (size_t)b * L_S;
  const int q = qs + l31;
  const size_t rowQ = (bL + q) * QW + h * HD;
  // Q as B-frags: qf[ds] = Q[q][ds*16 + hi*8 .. +7]
  short8 qf[8];
#pragma unroll
  for (int ds = 0; ds < 8; ++ds)
    qf[ds] = *(const short8*)(QKV + rowQ + ds * 16 + hi * 8);
  f32x16 o[4];
#pragma unroll
  for (int dt = 0; dt < 4; ++dt)
#pragma unroll
    for (int r = 0; r < 16; ++r) o[dt][r] = 0.f;
  float m2 = -3e38f, lsum = 0.f;  // per-lane stats for this lane's q (log2 domain)
  int t0 = qb * 256 - (WIN - 1);
  if (t0 < 0) t0 = 0;
  t0 >>= 6;
  const int t1 = 4 * qb + 3;  // == (qb*256+255)>>6
  short8 vreg[2];

  // --- staging helpers (512 threads) ---
  auto ISSUE_K = [&](int t, int buf) {
    char* Kb = (char*)Klds + buf * 16384;
#pragma unroll
    for (int rr = 0; rr < 2; ++rr) {
      int row = rr * 32 + (tid >> 4);              // 0..63
      int colb = ((tid & 15) * 16) ^ ((row & 7) << 4);  // inverse-swizzled source
      gload_lds16(QKV + (bL + t * 64 + row) * QW + E_D + kh * HD + (colb >> 1),
                  Kb + rr * 8192 + w * 1024 + (lane << 4));
    }
  };
  auto LOAD_V = [&](int t) {
#pragma unroll
    for (int rr = 0; rr < 2; ++rr)
      vreg[rr] = *(const short8*)(QKV + (bL + t * 64 + lane) * QW + E_D + 512 + kh * HD +
                                  ((w * 2 + rr) * 8));
  };
  auto WRITE_V = [&](int buf) {
    char* Vb = (char*)Vt + buf * 16384;
#pragma unroll
    for (int rr = 0; rr < 2; ++rr) {
      int db = (w * 2 + rr) * 8;                   // multiple of 8 -> row&7 == e
#pragma unroll
      for (int e = 0; e < 8; ++e)
        *(u16*)(Vb + ((((db + e) * 128) + lane * 2) ^ (e << 4))) = (u16)vreg[rr][e];
    }
  };

  // --- prologue: stage tile t0 ---
  LOAD_V(t0);
  ISSUE_K(t0, 0);
  __syncthreads();          // drains K gloads + V reg loads
  WRITE_V(0);               // Vt[0] = V(t0); published by barrier1 of iter t0
  int c = 0;

  for (int t = t0; t <= t1; ++t) {
    const int kv0 = t * 64;
    const int tn = (t < t1) ? t + 1 : t1;
    // prefetch next tile: K -> Klds[c^1] (async), V -> regs. Both fly until barrier1.
    ISSUE_K(tn, c ^ 1);
    LOAD_V(tn);
    // per-wave activity: does [kv0, kv0+63] intersect this wave's allowed range?
    const bool act = (kv0 <= qs + 31) && (kv0 + 63 > qs - WIN);
    u32x4 pa[4];  // assembled PV A-frags (bf16 x8 each)
    if (act) {
      // --- S^T = K Q^T from Klds[c]: two 32-kv groups, 8 d-slices each ---
      char* Kb = (char*)Klds + c * 16384;
      f32x16 s[2];
#pragma unroll
      for (int g = 0; g < 2; ++g)
#pragma unroll
        for (int r = 0; r < 16; ++r) s[g][r] = 0.f;
#pragma unroll
      for (int g = 0; g < 2; ++g) {
        const int r = g * 32 + l31;                  // K row this lane reads
        const int rsw = (r & 7) << 4;
#pragma unroll
        for (int ds = 0; ds < 8; ++ds) {
          short8 kf = *(const short8*)(Kb + (r * 256 + ((ds * 32 + hi * 16) ^ rsw)));
          s[g] = __builtin_amdgcn_mfma_f32_32x32x16_bf16(kf, qf[ds], s[g], 0, 0, 0);
        }
      }
      // --- masked scores (log2 domain); kv = kv0+g*32+(r&3)+8*(r>>2)+4*hi ---
      float v[2][16];
      float mx = -3e38f;
#pragma unroll
      for (int g = 0; g < 2; ++g)
#pragma unroll
        for (int r = 0; r < 16; ++r) {
          int kg = kv0 + g * 32 + (r & 3) + 8 * (r >> 2) + 4 * hi;
          bool a = (kg <= q) && (kg > q - WIN);
          float vv = a ? s[g][r] * SCL2 : -3e38f;
          v[g][r] = vv;
          mx = fmaxf(mx, vv);
        }
      mx = fmaxf(mx, __shfl_xor(mx, 32));            // partner has other kv half
      // defer-max (T13): 8 nats = 11.5416 bits; wave-uniform branch
      if (__ballot(mx > m2 + 11.5415603f)) {
        float mn = fmaxf(m2, mx);
        float alpha = exp2f(m2 - mn);
        m2 = mn;
        lsum *= alpha;
#pragma unroll
        for (int r = 0; r < 16; ++r) {
          float alr = __shfl(alpha, (r & 3) + 8 * (r >> 2) + 4 * hi);
#pragma unroll
          for (int dt = 0; dt < 4; ++dt) o[dt][r] *= alr;
        }
      }
      // exp + sum
      float rs = 0.f;
#pragma unroll
      for (int g = 0; g < 2; ++g)
#pragma unroll
        for (int r = 0; r < 16; ++r) {
          float pe = (v[g][r] > -1e37f) ? exp2f(v[g][r] - m2) : 0.f;
          v[g][r] = pe;
          rs += pe;
        }
      rs += __shfl_xor(rs, 32);
      lsum += rs;
      // --- P stays in registers: pack words + partner exchange ---
      // W[g][2qi+u] covers kv = g*32 + 8*qi + 4*hi + {2u, 2u+1}
#pragma unroll
      for (int g = 0; g < 2; ++g) {
        u32 W[8];
#pragma unroll
        for (int qi = 0; qi < 4; ++qi) {
          W[2 * qi]     = pack_bf16_pair(v[g][4 * qi + 0], v[g][4 * qi + 1]);
          W[2 * qi + 1] = pack_bf16_pair(v[g][4 * qi + 2], v[g][4 * qi + 3]);
        }
        // supply what partner needs; receive what we need (symmetric xor-32)
        u32 R[4];
        R[0] = __shfl_xor(hi ? W[0] : W[2], 32);
        R[1] = __shfl_xor(hi ? W[1] : W[3], 32);
        R[2] = __shfl_xor(hi ? W[4] : W[6], 32);
        R[3] = __shfl_xor(hi ? W[5] : W[7], 32);
        // frag(ksl): kv = (g*2+ksl)*16 + hi*8 + 0..7, kv-ascending
#pragma unroll
        for (int ksl = 0; ksl < 2; ++ksl) {
          u32x4 fr;
          if (hi == 0) {
            fr[0] = W[4 * ksl]; fr[1] = W[4 * ksl + 1];
            fr[2] = R[2 * ksl]; fr[3] = R[2 * ksl + 1];
          } else {
            fr[0] = R[2 * ksl]; fr[1] = R[2 * ksl + 1];
            fr[2] = W[4 * ksl + 2]; fr[3] = W[4 * ksl + 3];
          }
          pa[g * 2 + ksl] = fr;
        }
      }
    }
    __syncthreads();  // barrier1: drains K(tn)+V(tn) loads; publishes Vt[c]; orders reuse
    WRITE_V(c ^ 1);   // stage V(tn) into spare buffer (PV below reads Vt[c])
    if (act) {
      // --- O += P V from Vt[c] ---
      char* Vb = (char*)Vt + c * 16384;
      __builtin_amdgcn_s_setprio(1);
#pragma unroll
      for (int dt = 0; dt < 4; ++dt) {
        const int d = dt * 32 + l31;
        const int dsw = (d & 7) << 4;
#pragma unroll
        for (int ks = 0; ks < 4; ++ks) {
          short8 vf = *(const short8*)(Vb + (d * 128 + ((ks * 32 + hi * 16) ^ dsw)));
          o[dt] = __builtin_amdgcn_mfma_f32_32x32x16_bf16(
              __builtin_bit_cast(short8, pa[ks]), vf, o[dt], 0, 0, 0);
        }
      }
      __builtin_amdgcn_s_setprio(0);
    }
    c ^= 1;
  }
  // epilogue: normalize and write. o rows are q' = qs+(r&3)+8*(r>>2)+4*hi, col = dt*32+l31
  float inv = 1.0f / lsum;
#pragma unroll
  for (int r = 0; r < 16; ++r) {
    int ridx = (r & 3) + 8 * (r >> 2) + 4 * hi;
    float invr = __shfl(inv, ridx);
    size_t rowO = (bL + qs + ridx) * QW + h * HD + l31;
#pragma unroll
    for (int dt = 0; dt < 4; ++dt)
      QKV[rowO + dt * 32] = f32_bf16(o[dt][r] * invr);
  }
}

extern "C" void kernel_launch(void* const* d_in, const int* in_sizes, int n_in,
                              void* d_out, int out_size, void* d_ws, size_t ws_size,
                              hipStream_t stream) {
  const float* x  = (const float*)d_in[0];
  const float* Wq = (const float*)d_in[1];
  const float* Wk = (const float*)d_in[2];
  const float* Wv = (const float*)d_in[3];
  const float* Wo = (const float*)d_in[4];
  char* ws = (char*)d_ws;
  // Workspace layout (total 105,906,176 B). If the harness workspace is too
  // small, bail out cleanly (validation fails loudly instead of GPU faulting).
  if (ws_size < 105906176u) return;
  u16* xb    = (u16*)(ws);                    // 8192*2048*2 = 33554432
  u16* Wqkv  = (u16*)(ws + 33554432);         // 3072*2048*2 = 12582912
  u16* Wob   = (u16*)(ws + 46137344);         // 2048*2048*2 =  8388608
  u16* QKV   = (u16*)(ws + 54525952);         // 8192*3072*2 = 50331648
  float* cs  = (float*)(ws + 104857600);      // 131072*4    =   524288
  float* sn  = (float*)(ws + 105381888);      // total end 105906176 B

  // bf16 casts (weights packed: Wq rows 0..2047 | Wk rows 2048..2559 | Wv rows 2560..3071)
  k_cast<<<8192, 256, 0, stream>>>(x, xb, 16777216 / 8);
  k_cast<<<2048, 256, 0, stream>>>(Wq, Wqkv, 4194304 / 8);
  k_cast<<<512, 256, 0, stream>>>(Wk, Wqkv + 2048 * 2048, 1048576 / 8);
  k_cast<<<512, 256, 0, stream>>>(Wv, Wqkv + 2560 * 2048, 1048576 / 8);
  k_cast<<<2048, 256, 0, stream>>>(Wo, Wob, 4194304 / 8);
  k_rope_table<<<512, 256, 0, stream>>>(cs, sn);
  // fused QKV projection: [Q|K|V] = xb @ Wqkv^T
  k_gemm_bt<0><<<dim3(64, 24), 256, 0, stream>>>(xb, 2048, Wqkv, 2048, QKV, QW, 2048);
  // RoPE in place on Q and K regions
  k_rope_apply<<<40960, 256, 0, stream>>>(QKV, cs, sn);
  // flash attention; Z overwrites Q region of QKV
  k_attn<<<dim3(8, 16, 4), 512, 0, stream>>>(QKV);
  // out = Z @ Wo^T (fp32 out)
  k_gemm_bt<1><<<dim3(64, 16), 256, 0, stream>>>(QKV, QW, Wob, 2048, d_out, 2048, 2048);
}

// Round 16
// 427.314 us; speedup vs baseline: 1.8172x; 1.0227x over previous
//
#include <hip/hip_runtime.h>
#include <hip/hip_bf16.h>
#include <math.h>

typedef unsigned short u16;
typedef unsigned int u32;
typedef __attribute__((ext_vector_type(8))) short short8;
typedef __attribute__((ext_vector_type(8))) u16 ushort8;
typedef __attribute__((ext_vector_type(4))) float f32x4;
typedef __attribute__((ext_vector_type(16))) float f32x16;
typedef __attribute__((ext_vector_type(4))) u32 u32x4;

#define N_B 4
#define L_S 2048
#define E_D 2048
#define NH 16
#define HD 128
#define WIN 1024
#define QW 3072  // QKV buffer row width: 2048 q | 512 k | 512 v
#define LOG2E 1.4426950408889634f

static __device__ __forceinline__ u16 f32_bf16(float f) {
  u32 u = __builtin_bit_cast(u32, f);
  u = (u + 0x7fffu + ((u >> 16) & 1u)) >> 16;  // RNE
  return (u16)u;
}
static __device__ __forceinline__ float bf16_f32(u16 h) {
  u32 u = ((u32)h) << 16;
  return __builtin_bit_cast(float, u);
}
static __device__ __forceinline__ u32 pack_bf16_pair(float lo, float hi) {
  __hip_bfloat162 h2 = __float22bfloat162_rn(make_float2(lo, hi));  // RNE, .x = low
  u32 r;
  __builtin_memcpy(&r, &h2, 4);
  return r;
}
static __device__ __forceinline__ void gload_lds16(const void* g, void* l) {
  __builtin_amdgcn_global_load_lds((__attribute__((address_space(1))) void*)g,
                                   (__attribute__((address_space(3))) void*)l, 16, 0, 0);
}

// ---------------- fp32 -> bf16 cast (n multiple of 8) ----------------
__global__ void k_cast(const float* __restrict__ src, u16* __restrict__ dst, int n8) {
  int i = blockIdx.x * blockDim.x + threadIdx.x;
  if (i >= n8) return;
  const float4* s = (const float4*)src + (size_t)i * 2;
  float4 a = s[0], b = s[1];
  ushort8 v;
  v[0] = f32_bf16(a.x); v[1] = f32_bf16(a.y); v[2] = f32_bf16(a.z); v[3] = f32_bf16(a.w);
  v[4] = f32_bf16(b.x); v[5] = f32_bf16(b.y); v[6] = f32_bf16(b.z); v[7] = f32_bf16(b.w);
  *((ushort8*)dst + i) = v;
}

// ---------------- RoPE cos/sin table: [L][64] ----------------
__global__ void k_rope_table(float* __restrict__ cs, float* __restrict__ sn) {
  int idx = blockIdx.x * blockDim.x + threadIdx.x;  // 2048*64
  int l = idx >> 6, f = idx & 63;
  float freq = exp2f(-(float)f * (13.287712379549449f / 64.0f));  // 10000^(-2f/128)
  float ang = (float)l * freq;
  cs[idx] = cosf(ang);
  sn[idx] = sinf(ang);
}

// ---------------- interleaved RoPE applied in place to Q and K of QKV ----------------
__global__ void k_rope_apply(u16* __restrict__ QKV, const float* __restrict__ cs,
                             const float* __restrict__ sn) {
  int idx = blockIdx.x * blockDim.x + threadIdx.x;  // 8192*20*64 exactly
  int f = idx & 63;
  int rest = idx >> 6;
  int hh = rest % 20;          // 0..15 q heads, 16..19 kv heads
  int row = rest / 20;         // 0..8191 (= n*L + l)
  int l = row & (L_S - 1);
  int col = (hh < NH) ? (hh * HD + 2 * f) : (E_D + (hh - NH) * HD + 2 * f);
  u32* p = (u32*)(QKV + (size_t)row * QW + col);
  u32 v = *p;
  float xr = bf16_f32((u16)(v & 0xffffu));
  float xi = bf16_f32((u16)(v >> 16));
  float c = cs[l * 64 + f], s = sn[l * 64 + f];
  float orr = xr * c - xi * s;
  float oii = xr * s + xi * c;
  *p = (u32)f32_bf16(orr) | ((u32)f32_bf16(oii) << 16);
}

// ---------------- C = A @ B^T, 256x256 tile, BK=32, 3-buf counted-vmcnt pipeline ----
// A: MxK row-major (lda), B: NxK row-major (ldb), bf16; C bf16 or f32.
// 8 waves (2M x 4N), per-wave 128x64 output, acc[8][4] f32x4.
// LDS: 3 bufs x ([256][32] A + [256][32] B) = 96 KB, 64B rows.
// Swizzle: col_byte ^= (row&6)<<3 (both sides: pre-swizzled gload SOURCE with
// linear LDS dest, and identical XOR on ds_read) -> frag reads 2-way (free).
// Pipeline: stage(t+2) issued at iter t; pre-barrier s_waitcnt vmcnt(4) keeps
// tile t+2's 4 loads in flight across the RAW s_barrier (no compiler drain);
// lgkmcnt(0) prevents cross-wave WAR on in-flight ds_reads (buf c rewritten at
// t+1 only after barrier(t)). sched_barrier(0) fences per lesson #18.
// XCD A-panel blocking: fid&7 = XCD; each XCD owns 4 m-tiles (A-panel 4 MB =
// L2-size) x all n-tiles -> A re-reads become L2 hits.
template <int OUT_F32>
__global__ __launch_bounds__(512, 1) void k_gemm256(
    const u16* __restrict__ A, int lda,
    const u16* __restrict__ B, int ldb,
    void* __restrict__ Cp, int ldc, int K) {
  __shared__ __align__(16) u16 Ab[3 * 8192];  // 3 x [256][32]
  __shared__ __align__(16) u16 Bb[3 * 8192];
  const int tid = threadIdx.x;
  const int lane = tid & 63, w = tid >> 6;
  const int lr = lane & 15, lg = lane >> 4;
  const int wm = w >> 2, wn = w & 3;
  const int fid = blockIdx.x;
  const int cc = fid & 7, l = fid >> 3;
  const int m0 = (cc * 4 + (l & 3)) * 256;
  const int n0 = (l >> 2) * 256;
  const int rswz = (lr & 6) << 3;  // read-side XOR (row bits 1-2)

  auto STAGE = [&](int kt, int bb) {
    const int r2 = tid >> 2;                               // 0..127
    const int ce = (((tid & 3) * 16) ^ ((r2 & 6) << 3)) >> 1;  // pre-swizzled src col (elems)
#pragma unroll
    for (int rr = 0; rr < 2; ++rr) {
      int row = rr * 128 + r2;
      gload_lds16(A + (size_t)(m0 + row) * lda + kt * 32 + ce,
                  (char*)Ab + bb * 16384 + rr * 8192 + (w << 10));
      gload_lds16(B + (size_t)(n0 + row) * ldb + kt * 32 + ce,
                  (char*)Bb + bb * 16384 + rr * 8192 + (w << 10));
    }
  };

  f32x4 acc[8][4];
  const f32x4 z4 = {0.f, 0.f, 0.f, 0.f};
#pragma unroll
  for (int mf = 0; mf < 8; ++mf)
#pragma unroll
    for (int nf = 0; nf < 4; ++nf) acc[mf][nf] = z4;

  const int nt = K >> 5;  // K-tiles of 32 (K=2048 -> 64; requires nt >= 3)
  STAGE(0, 0);
  STAGE(1, 1);
  asm volatile("s_waitcnt vmcnt(4)" ::: "memory");  // tile0's 4 loads done; tile1 in flight
  __builtin_amdgcn_sched_barrier(0);
  __builtin_amdgcn_s_barrier();
  __builtin_amdgcn_sched_barrier(0);

  int c3 = 0;
  for (int t = 0; t < nt; ++t) {
    int ib = c3 + 2; if (ib >= 3) ib -= 3;
    if (t + 2 < nt) STAGE(t + 2, ib);
    const char* Abt = (const char*)Ab + c3 * 16384;
    const char* Bbt = (const char*)Bb + c3 * 16384;
    short8 af[8], bf[4];
#pragma unroll
    for (int nf = 0; nf < 4; ++nf) {
      int row = wn * 64 + nf * 16 + lr;
      bf[nf] = *(const short8*)(Bbt + row * 64 + ((lg * 16) ^ rswz));
    }
#pragma unroll
    for (int mf = 0; mf < 8; ++mf) {
      int row = wm * 128 + mf * 16 + lr;
      af[mf] = *(const short8*)(Abt + row * 64 + ((lg * 16) ^ rswz));
    }
    __builtin_amdgcn_s_setprio(1);
#pragma unroll
    for (int mf = 0; mf < 8; ++mf)
#pragma unroll
      for (int nf = 0; nf < 4; ++nf)
        acc[mf][nf] =
            __builtin_amdgcn_mfma_f32_16x16x32_bf16(af[mf], bf[nf], acc[mf][nf], 0, 0, 0);
    __builtin_amdgcn_s_setprio(0);
    // publish tile t+1 (issued at iter t-1); keep tile t+2's 4 loads in flight
    if (t + 2 < nt)
      asm volatile("s_waitcnt vmcnt(4) lgkmcnt(0)" ::: "memory");
    else
      asm volatile("s_waitcnt vmcnt(0) lgkmcnt(0)" ::: "memory");
    __builtin_amdgcn_sched_barrier(0);
    __builtin_amdgcn_s_barrier();
    __builtin_amdgcn_sched_barrier(0);
    c3 = (c3 == 2) ? 0 : c3 + 1;
  }

#pragma unroll
  for (int mf = 0; mf < 8; ++mf)
#pragma unroll
    for (int nf = 0; nf < 4; ++nf)
#pragma unroll
      for (int j = 0; j < 4; ++j) {
        size_t r = (size_t)(m0 + wm * 128 + mf * 16 + lg * 4 + j);
        int c = n0 + wn * 64 + nf * 16 + lr;
        if (OUT_F32)
          ((float*)Cp)[r * ldc + c] = acc[mf][nf][j];
        else
          ((u16*)Cp)[r * ldc + c] = f32_bf16(acc[mf][nf][j]);
      }
}

// ---------------- sliding-window flash attention (pipelined, 8 waves, 32x32 MFMA) ----
// (unchanged from round 15 — passing, 437 us total)
__global__ __launch_bounds__(512, 2) void k_attn(u16* __restrict__ QKV) {
  const int bx = blockIdx.x, h = blockIdx.y, b = blockIdx.z;
  const int qb = (b >= 2) ? 7 - bx : bx;        // cost-balanced remap
  const int tid = threadIdx.x;
  const int lane = tid & 63, w = tid >> 6;      // 8 waves
  const int l31 = lane & 31, hi = lane >> 5;
  const int kh = h >> 2;
  const int qs = qb * 256 + w * 32;
  __shared__ __align__(16) u16 Klds[2][64 * 128];  // [kv][d], swizzled, 2 buffers
  __shared__ __align__(16) u16 Vt[2][128 * 64];    // [d][kv], swizzled, 2 buffers
  const float SCL2 = 0.08838834764831845f * 1.4426950408889634f;  // scale*log2(e)
  const size_t bL = (size_t)b * L_S;
  const int q = qs + l31;
  const size_t rowQ = (bL + q) * QW + h * HD;
  short8 qf[8];
#pragma unroll
  for (int ds = 0; ds < 8; ++ds)
    qf[ds] = *(const short8*)(QKV + rowQ + ds * 16 + hi * 8);
  f32x16 o[4];
#pragma unroll
  for (int dt = 0; dt < 4; ++dt)
#pragma unroll
    for (int r = 0; r < 16; ++r) o[dt][r] = 0.f;
  float m2 = -3e38f, lsum = 0.f;  // per-lane stats for this lane's q (log2 domain)
  int t0 = qb * 256 - (WIN - 1);
  if (t0 < 0) t0 = 0;
  t0 >>= 6;
  const int t1 = 4 * qb + 3;  // == (qb*256+255)>>6
  short8 vreg[2];

  auto ISSUE_K = [&](int t, int buf) {
    char* Kb = (char*)Klds + buf * 16384;
#pragma unroll
    for (int rr = 0; rr < 2; ++rr) {
      int row = rr * 32 + (tid >> 4);              // 0..63
      int colb = ((tid & 15) * 16) ^ ((row & 7) << 4);  // inverse-swizzled source
      gload_lds16(QKV + (bL + t * 64 + row) * QW + E_D + kh * HD + (colb >> 1),
                  Kb + rr * 8192 + w * 1024 + (lane << 4));
    }
  };
  auto LOAD_V = [&](int t) {
#pragma unroll
    for (int rr = 0; rr < 2; ++rr)
      vreg[rr] = *(const short8*)(QKV + (bL + t * 64 + lane) * QW + E_D + 512 + kh * HD +
                                  ((w * 2 + rr) * 8));
  };
  auto WRITE_V = [&](int buf) {
    char* Vb = (char*)Vt + buf * 16384;
#pragma unroll
    for (int rr = 0; rr < 2; ++rr) {
      int db = (w * 2 + rr) * 8;                   // multiple of 8 -> row&7 == e
#pragma unroll
      for (int e = 0; e < 8; ++e)
        *(u16*)(Vb + ((((db + e) * 128) + lane * 2) ^ (e << 4))) = (u16)vreg[rr][e];
    }
  };

  LOAD_V(t0);
  ISSUE_K(t0, 0);
  __syncthreads();          // drains K gloads + V reg loads
  WRITE_V(0);               // Vt[0] = V(t0); published by barrier1 of iter t0
  int c = 0;

  for (int t = t0; t <= t1; ++t) {
    const int kv0 = t * 64;
    const int tn = (t < t1) ? t + 1 : t1;
    ISSUE_K(tn, c ^ 1);
    LOAD_V(tn);
    const bool act = (kv0 <= qs + 31) && (kv0 + 63 > qs - WIN);
    u32x4 pa[4];  // assembled PV A-frags (bf16 x8 each)
    if (act) {
      char* Kb = (char*)Klds + c * 16384;
      f32x16 s[2];
#pragma unroll
      for (int g = 0; g < 2; ++g)
#pragma unroll
        for (int r = 0; r < 16; ++r) s[g][r] = 0.f;
#pragma unroll
      for (int g = 0; g < 2; ++g) {
        const int r = g * 32 + l31;                  // K row this lane reads
        const int rsw = (r & 7) << 4;
#pragma unroll
        for (int ds = 0; ds < 8; ++ds) {
          short8 kf = *(const short8*)(Kb + (r * 256 + ((ds * 32 + hi * 16) ^ rsw)));
          s[g] = __builtin_amdgcn_mfma_f32_32x32x16_bf16(kf, qf[ds], s[g], 0, 0, 0);
        }
      }
      float v[2][16];
      float mx = -3e38f;
#pragma unroll
      for (int g = 0; g < 2; ++g)
#pragma unroll
        for (int r = 0; r < 16; ++r) {
          int kg = kv0 + g * 32 + (r & 3) + 8 * (r >> 2) + 4 * hi;
          bool a = (kg <= q) && (kg > q - WIN);
          float vv = a ? s[g][r] * SCL2 : -3e38f;
          v[g][r] = vv;
          mx = fmaxf(mx, vv);
        }
      mx = fmaxf(mx, __shfl_xor(mx, 32));            // partner has other kv half
      if (__ballot(mx > m2 + 11.5415603f)) {
        float mn = fmaxf(m2, mx);
        float alpha = exp2f(m2 - mn);
        m2 = mn;
        lsum *= alpha;
#pragma unroll
        for (int r = 0; r < 16; ++r) {
          float alr = __shfl(alpha, (r & 3) + 8 * (r >> 2) + 4 * hi);
#pragma unroll
          for (int dt = 0; dt < 4; ++dt) o[dt][r] *= alr;
        }
      }
      float rs = 0.f;
#pragma unroll
      for (int g = 0; g < 2; ++g)
#pragma unroll
        for (int r = 0; r < 16; ++r) {
          float pe = (v[g][r] > -1e37f) ? exp2f(v[g][r] - m2) : 0.f;
          v[g][r] = pe;
          rs += pe;
        }
      rs += __shfl_xor(rs, 32);
      lsum += rs;
#pragma unroll
      for (int g = 0; g < 2; ++g) {
        u32 W[8];
#pragma unroll
        for (int qi = 0; qi < 4; ++qi) {
          W[2 * qi]     = pack_bf16_pair(v[g][4 * qi + 0], v[g][4 * qi + 1]);
          W[2 * qi + 1] = pack_bf16_pair(v[g][4 * qi + 2], v[g][4 * qi + 3]);
        }
        u32 R[4];
        R[0] = __shfl_xor(hi ? W[0] : W[2], 32);
        R[1] = __shfl_xor(hi ? W[1] : W[3], 32);
        R[2] = __shfl_xor(hi ? W[4] : W[6], 32);
        R[3] = __shfl_xor(hi ? W[5] : W[7], 32);
#pragma unroll
        for (int ksl = 0; ksl < 2; ++ksl) {
          u32x4 fr;
          if (hi == 0) {
            fr[0] = W[4 * ksl]; fr[1] = W[4 * ksl + 1];
            fr[2] = R[2 * ksl]; fr[3] = R[2 * ksl + 1];
          } else {
            fr[0] = R[2 * ksl]; fr[1] = R[2 * ksl + 1];
            fr[2] = W[4 * ksl + 2]; fr[3] = W[4 * ksl + 3];
          }
          pa[g * 2 + ksl] = fr;
        }
      }
    }
    __syncthreads();  // barrier1: drains K(tn)+V(tn) loads; publishes Vt[c]; orders reuse
    WRITE_V(c ^ 1);   // stage V(tn) into spare buffer (PV below reads Vt[c])
    if (act) {
      char* Vb = (char*)Vt + c * 16384;
      __builtin_amdgcn_s_setprio(1);
#pragma unroll
      for (int dt = 0; dt < 4; ++dt) {
        const int d = dt * 32 + l31;
        const int dsw = (d & 7) << 4;
#pragma unroll
        for (int ks = 0; ks < 4; ++ks) {
          short8 vf = *(const short8*)(Vb + (d * 128 + ((ks * 32 + hi * 16) ^ dsw)));
          o[dt] = __builtin_amdgcn_mfma_f32_32x32x16_bf16(
              __builtin_bit_cast(short8, pa[ks]), vf, o[dt], 0, 0, 0);
        }
      }
      __builtin_amdgcn_s_setprio(0);
    }
    c ^= 1;
  }
  float inv = 1.0f / lsum;
#pragma unroll
  for (int r = 0; r < 16; ++r) {
    int ridx = (r & 3) + 8 * (r >> 2) + 4 * hi;
    float invr = __shfl(inv, ridx);
    size_t rowO = (bL + qs + ridx) * QW + h * HD + l31;
#pragma unroll
    for (int dt = 0; dt < 4; ++dt)
      QKV[rowO + dt * 32] = f32_bf16(o[dt][r] * invr);
  }
}

extern "C" void kernel_launch(void* const* d_in, const int* in_sizes, int n_in,
                              void* d_out, int out_size, void* d_ws, size_t ws_size,
                              hipStream_t stream) {
  const float* x  = (const float*)d_in[0];
  const float* Wq = (const float*)d_in[1];
  const float* Wk = (const float*)d_in[2];
  const float* Wv = (const float*)d_in[3];
  const float* Wo = (const float*)d_in[4];
  char* ws = (char*)d_ws;
  // Workspace layout (total 105,906,176 B). If the harness workspace is too
  // small, bail out cleanly (validation fails loudly instead of GPU faulting).
  if (ws_size < 105906176u) return;
  u16* xb    = (u16*)(ws);                    // 8192*2048*2 = 33554432
  u16* Wqkv  = (u16*)(ws + 33554432);         // 3072*2048*2 = 12582912
  u16* Wob   = (u16*)(ws + 46137344);         // 2048*2048*2 =  8388608
  u16* QKV   = (u16*)(ws + 54525952);         // 8192*3072*2 = 50331648
  float* cs  = (float*)(ws + 104857600);      // 131072*4    =   524288
  float* sn  = (float*)(ws + 105381888);      // total end 105906176 B

  // bf16 casts (weights packed: Wq rows 0..2047 | Wk rows 2048..2559 | Wv rows 2560..3071)
  k_cast<<<8192, 256, 0, stream>>>(x, xb, 16777216 / 8);
  k_cast<<<2048, 256, 0, stream>>>(Wq, Wqkv, 4194304 / 8);
  k_cast<<<512, 256, 0, stream>>>(Wk, Wqkv + 2048 * 2048, 1048576 / 8);
  k_cast<<<512, 256, 0, stream>>>(Wv, Wqkv + 2560 * 2048, 1048576 / 8);
  k_cast<<<2048, 256, 0, stream>>>(Wo, Wob, 4194304 / 8);
  k_rope_table<<<512, 256, 0, stream>>>(cs, sn);
  // fused QKV projection: [Q|K|V] = xb @ Wqkv^T  (256^2 tiles: 32 m x 12 n = 384 wg)
  k_gemm256<0><<<384, 512, 0, stream>>>(xb, 2048, Wqkv, 2048, QKV, QW, 2048);
  // RoPE in place on Q and K regions
  k_rope_apply<<<40960, 256, 0, stream>>>(QKV, cs, sn);
  // flash attention; Z overwrites Q region of QKV
  k_attn<<<dim3(8, 16, 4), 512, 0, stream>>>(QKV);
  // out = Z @ Wo^T (fp32 out; 32 m x 8 n = 256 wg)
  k_gemm256<1><<<256, 512, 0, stream>>>(QKV, QW, Wob, 2048, d_out, 2048, 2048);
}